// Round 10
// baseline (289.028 us; speedup 1.0000x reference)
//
#include <hip/hip_runtime.h>
#include <cmath>

// MHA fused forward, MI355X gfx950.
// R9: gemm_qk256 rebuilt as a faithful 8-phase/2-tile (4 phases per K-tile)
//     schedule (m201 template): per phase {ds_read subtile || stage 1
//     half-tile -> barrier -> setprio(1) 16 MFMA setprio(0) -> barrier},
//     ONE counted s_waitcnt vmcnt(2) per tile at phase 0 (loads stay in
//     flight across barriers). R8's coarse 2-phase variant reproduced the
//     documented 2-phase ceiling (644 vs m233's 607 TF) -- the fine
//     interleave is the gated lever (m196/m218/m230).
// V on the proven 128x128 m97 kernel; attn/gemm_o/prep unchanged (R7).
// Numerics: split-bf16 hi/lo 3-term for Q/K projections and QK^T.

typedef __bf16 bf16_t;
typedef __bf16 bf16x2 __attribute__((ext_vector_type(2)));
typedef __bf16 bf16x4 __attribute__((ext_vector_type(4)));
typedef __bf16 bf16x8 __attribute__((ext_vector_type(8)));
typedef float f32x2 __attribute__((ext_vector_type(2)));
typedef float f32x4 __attribute__((ext_vector_type(4)));
typedef unsigned int u32;
typedef const __attribute__((address_space(1))) u32* gaddr_t;
typedef __attribute__((address_space(3))) u32* saddr_t;

struct RopeTab { float inv[32]; };

// ---------------- fused pre-pass ----------------
__device__ __forceinline__ void split4(const float* __restrict__ in,
                                       bf16_t* __restrict__ hi,
                                       bf16_t* __restrict__ lo, bool LO,
                                       int blk, int tid)
{
  const int i = blk * 256 + tid;
  const f32x4 u = *(const f32x4*)(in + (size_t)i * 4);
  bf16x4 h, l;
  #pragma unroll
  for (int j = 0; j < 4; ++j) {
    const bf16_t hb = (bf16_t)u[j];
    h[j] = hb;
    if (LO) l[j] = (bf16_t)(u[j] - (float)hb);
  }
  *(bf16x4*)(hi + (size_t)i * 4) = h;
  if (LO) *(bf16x4*)(lo + (size_t)i * 4) = l;
}

__global__ __launch_bounds__(256) void prep_k(
    const float* __restrict__ x,  const float* __restrict__ qw,
    const float* __restrict__ kw, const float* __restrict__ vw,
    const float* __restrict__ ow, RopeTab tab,
    bf16_t* __restrict__ Xh,  bf16_t* __restrict__ Xl,
    bf16_t* __restrict__ QWh, bf16_t* __restrict__ QWl,
    bf16_t* __restrict__ KWh, bf16_t* __restrict__ KWl,
    bf16_t* __restrict__ VWh, bf16_t* __restrict__ OWh,
    float* __restrict__ ropeT)
{
  const int bid = blockIdx.x, tid = threadIdx.x;
  if (bid < 8192)       split4(x,  Xh,  Xl,  true,  bid,         tid);
  else if (bid < 9216)  split4(qw, QWh, QWl, true,  bid - 8192,  tid);
  else if (bid < 10240) split4(kw, KWh, KWl, true,  bid - 9216,  tid);
  else if (bid < 11264) split4(vw, VWh, nullptr, false, bid - 10240, tid);
  else if (bid < 12288) split4(ow, OWh, nullptr, false, bid - 11264, tid);
  else {
    const int i = (bid - 12288) * 256 + tid;   // 2048*32 entries
    const int p = i >> 5, d2 = i & 31;
    float sn, cs;
    sincosf((float)p * tab.inv[d2], &sn, &cs);
    ropeT[(size_t)i * 2]     = cs;
    ropeT[(size_t)i * 2 + 1] = sn;
  }
}

// ======== Q/K projection GEMM: 256x256, BK=64, 4-phase/K-tile pipeline ====
// z=0: Q, z=1: K. K_eff=3072 (segments hh, hl, lh). RoPE epilogue -> hi/lo out.
__global__ __launch_bounds__(512, 1) void gemm_qk256(
    const bf16_t* __restrict__ Xh, const bf16_t* __restrict__ Xl,
    const bf16_t* __restrict__ QWh, const bf16_t* __restrict__ QWl,
    const bf16_t* __restrict__ KWh, const bf16_t* __restrict__ KWl,
    const int* __restrict__ tokpos, const float* __restrict__ ropeT,
    bf16_t* __restrict__ Oq_h, bf16_t* __restrict__ Oq_l,
    bf16_t* __restrict__ Ok_h, bf16_t* __restrict__ Ok_l)
{
  __shared__ __align__(16) bf16_t sA[2][256 * 64];   // 64 KB
  __shared__ __align__(16) bf16_t sB[2][256 * 64];   // 64 KB

  const int tid = threadIdx.x;            // 0..511
  const int lane = tid & 63, wv = tid >> 6;
  const int wr = wv >> 2, wc = wv & 3;    // 2 (M) x 4 (N) waves
  const int la = lane & 15, lb = lane >> 4;

  // XCD-chunked remap within the 128-block z-slice.
  const int lin  = (int)blockIdx.y * 32 + (int)blockIdx.x;  // 0..127
  const int lin2 = (lin & 7) * 16 + (lin >> 3);             // bijective
  const int bx = lin2 & 31, by = lin2 >> 5;
  const int row0 = bx * 256, col0 = by * 256;
  const int z = blockIdx.z;

  const bf16_t* Wh = z ? KWh : QWh;
  const bf16_t* Wl = z ? KWl : QWl;

  // staging geometry: each half-tile (128 rows x 64 cols, 16KB) = 2 x 16B
  // loads per thread. Linear LDS dest, inverse-swizzled global chunk (#21).
  const int sr8  = tid >> 3;              // row within 64-row round
  const int scsw = (tid & 7) ^ (sr8 & 7); // swizzled source 16B chunk

  f32x4 acc[8][4] = {};                   // per-wave C: 128 x 64

  // h: 0 = A rows 0-127, 1 = A rows 128-255, 2 = B rows 0-127, 3 = B 128-255
  auto STAGE_H = [&](int t, int buf, int h) {
    const int seg = t >> 4;
    const int k0 = (t & 15) << 6;
    const bf16_t* src = (h < 2) ? ((seg == 2) ? Xl : Xh)
                                : ((seg == 1) ? Wl : Wh);
    bf16_t* dstb = (h < 2) ? &sA[buf][0] : &sB[buf][0];
    const int base_ = (h < 2) ? row0 : col0;
    const int half = h & 1;
    #pragma unroll
    for (int j = 0; j < 2; ++j) {
      const int jr = half * 2 + j;        // 64-row round index 0..3
      const int r = jr * 64 + sr8;
      __builtin_amdgcn_global_load_lds(
          (gaddr_t)(src + (size_t)(base_ + r) * 1024 + k0 + scsw * 8),
          (saddr_t)(dstb + jr * 4096 + tid * 8), 16, 0, 0);
    }
  };

  const int NT = 48;
  // prologue: stage tile 0 fully (8 loads), order A0,A1,B0,B1
  #pragma unroll
  for (int h = 0; h < 4; ++h) STAGE_H(0, 0, h);

  for (int t = 0; t < NT; ++t) {
    const int buf = t & 1, nbuf = buf ^ 1;
    const bf16_t* cA = &sA[buf][0];
    const bf16_t* cB = &sB[buf][0];
    bf16x8 bfr[4];

    #pragma unroll
    for (int p = 0; p < 4; ++p) {
      const int ks = p >> 1, mh = p & 1;
      bf16x8 afr[4];
      const int kcol = ((ks * 4 + lb) ^ (la & 7)) * 8;

      if (p == 0) {
        // tile boundary: issue first half-tile of t+1, counted wait for t.
        if (t + 1 < NT) {
          STAGE_H(t + 1, nbuf, 0);
          asm volatile("s_waitcnt vmcnt(2)" ::: "memory");  // t's 8 done
        } else {
          asm volatile("s_waitcnt vmcnt(0)" ::: "memory");
        }
        __builtin_amdgcn_s_barrier();      // tile t fully visible
        #pragma unroll
        for (int nf = 0; nf < 4; ++nf)
          bfr[nf] = *(const bf16x8*)&cB[(wc * 64 + nf * 16 + la) * 64 + kcol];
        #pragma unroll
        for (int i = 0; i < 4; ++i)
          afr[i] = *(const bf16x8*)&cA[(wr * 128 + i * 16 + la) * 64 + kcol];
      } else {
        // data already guaranteed; ds_read BEFORE barrier hides latency
        if (mh == 0) {   // p==2: fresh B frags for ks=1
          #pragma unroll
          for (int nf = 0; nf < 4; ++nf)
            bfr[nf] = *(const bf16x8*)&cB[(wc * 64 + nf * 16 + la) * 64 + kcol];
        }
        #pragma unroll
        for (int i = 0; i < 4; ++i)
          afr[i] = *(const bf16x8*)&cA[(wr * 128 + (mh * 4 + i) * 16 + la) * 64 + kcol];
        if (t + 1 < NT) STAGE_H(t + 1, nbuf, p);
        __builtin_amdgcn_s_barrier();
      }

      __builtin_amdgcn_s_setprio(1);
      #pragma unroll
      for (int i = 0; i < 4; ++i)
        #pragma unroll
        for (int nf = 0; nf < 4; ++nf)
          acc[mh * 4 + i][nf] =
              __builtin_amdgcn_mfma_f32_16x16x32_bf16(afr[i], bfr[nf], acc[mh * 4 + i][nf], 0, 0, 0);
      __builtin_amdgcn_s_setprio(0);
      __builtin_amdgcn_s_barrier();
    }
  }

  // ---- epilogue: RoPE via table -> hi/lo bf16 [B,H,S,D] ----
  bf16_t* Oh = z ? Ok_h : Oq_h;
  bf16_t* Ol = z ? Ok_l : Oq_l;
  #pragma unroll
  for (int n = 0; n < 4; ++n) {
    const int gn = col0 + wc * 64 + n * 16 + la;
    const int d = gn & 63, h = gn >> 6;
    const bool odd = d & 1;
    #pragma unroll
    for (int m = 0; m < 8; ++m) {
      const int gm0 = row0 + wr * 128 + m * 16 + lb * 4;
      #pragma unroll
      for (int j = 0; j < 4; ++j) {
        const int gm = gm0 + j;
        const float t = acc[m][n][j];
        const float other = __shfl_xor(t, 1, 64);   // partner column d^1
        const int pos = tokpos[gm];
        const f32x2 cs2 = *(const f32x2*)&ropeT[((size_t)pos << 6) + ((d >> 1) << 1)];
        const float r = odd ? (other * cs2[1] + t * cs2[0])
                            : (t * cs2[0] - other * cs2[1]);
        const bf16_t hb = (bf16_t)r;
        const int b = gm >> 11, s = gm & 2047;
        const size_t oi = (((size_t)b * 16 + h) * 2048 + s) * 64 + d;
        Oh[oi] = hb;
        Ol[oi] = (bf16_t)(r - (float)hb);
      }
    }
  }
}

// ------------- V projection GEMM (B^T), m97 single-buffer 128x128 -------------
__global__ __launch_bounds__(256, 4) void gemm_qkv(
    const bf16_t* __restrict__ Xh, const bf16_t* __restrict__ Xl,
    const bf16_t* __restrict__ QWh, const bf16_t* __restrict__ QWl,
    const bf16_t* __restrict__ KWh, const bf16_t* __restrict__ KWl,
    const bf16_t* __restrict__ VWh,
    const int* __restrict__ tokpos, const float* __restrict__ ropeT,
    bf16_t* __restrict__ Oq_h, bf16_t* __restrict__ Oq_l,
    bf16_t* __restrict__ Ok_h, bf16_t* __restrict__ Ok_l,
    bf16_t* __restrict__ Vt, int zbase)
{
  __shared__ __align__(16) bf16_t sA[128 * 64];
  __shared__ __align__(16) bf16_t sB[128 * 64];

  const int tid = threadIdx.x;
  const int lane = tid & 63, wv = tid >> 6;
  const int wr = wv >> 1, wc = wv & 1;
  const int la = lane & 15, lb = lane >> 4;
  const int row0 = blockIdx.x * 128, col0 = blockIdx.y * 128;
  const int z = blockIdx.z + zbase;

  const int srow = wv * 32 + (lane >> 3);   // + i*8
  const int schk = lane & 7;                // physical 16B chunk within row

  f32x4 acc[4][4] = {};

  const int NT = (z == 2) ? 16 : 48;        // steps of BK=64 (3 segs for Q/K)

  for (int t = 0; t < NT; ++t) {
    const int seg = t >> 4;
    const int k0 = (t & 15) << 6;
    const bf16_t* Ap = (z < 2 && seg == 2) ? Xl : Xh;
    const bf16_t* Wp = (z == 2) ? VWh
                     : (z == 1) ? ((seg == 1) ? KWl : KWh)
                                : ((seg == 1) ? QWl : QWh);
    __syncthreads();
    #pragma unroll
    for (int i = 0; i < 4; ++i) {
      const int r = srow + i * 8;
      const int cs_ = (schk ^ (r & 7)) * 8;       // inverse-swizzled source col
      __builtin_amdgcn_global_load_lds(
          (gaddr_t)(Ap + (size_t)(row0 + r) * 1024 + k0 + cs_),
          (saddr_t)(sA + wv * 2048 + i * 512), 16, 0, 0);
      __builtin_amdgcn_global_load_lds(
          (gaddr_t)(Wp + (size_t)(col0 + r) * 1024 + k0 + cs_),
          (saddr_t)(sB + wv * 2048 + i * 512), 16, 0, 0);
    }
    __syncthreads();

    #pragma unroll
    for (int ks = 0; ks < 2; ++ks) {
      bf16x8 af[4];
      #pragma unroll
      for (int m = 0; m < 4; ++m) {
        const int r = wr * 64 + m * 16 + la;
        af[m] = *(const bf16x8*)&sA[r * 64 + (((ks * 4 + lb) ^ (la & 7)) * 8)];
      }
      #pragma unroll
      for (int n = 0; n < 4; ++n) {
        const int r = wc * 64 + n * 16 + la;
        const bf16x8 bfr = *(const bf16x8*)&sB[r * 64 + (((ks * 4 + lb) ^ (la & 7)) * 8)];
        #pragma unroll
        for (int m = 0; m < 4; ++m)
          acc[m][n] = __builtin_amdgcn_mfma_f32_16x16x32_bf16(af[m], bfr, acc[m][n], 0, 0, 0);
      }
    }
  }

  // ---- epilogue ----
  #pragma unroll
  for (int n = 0; n < 4; ++n) {
    const int gn = col0 + wc * 64 + n * 16 + la;
    #pragma unroll
    for (int m = 0; m < 4; ++m) {
      const int gm0 = row0 + wr * 64 + m * 16 + lb * 4;
      if (z == 2) {
        // V^T layout: [B,H,D,S], packed 8B stores
        const int b = gm0 >> 11, s0 = gm0 & 2047;
        const int h = gn >> 6, d = gn & 63;
        bf16x4 v;
        #pragma unroll
        for (int j = 0; j < 4; ++j) v[j] = (bf16_t)acc[m][n][j];
        *(bf16x4*)&Vt[(((size_t)b * 16 + h) * 64 + d) * 2048 + s0] = v;
      } else {
        const int d = gn & 63, h = gn >> 6;
        const bool odd = d & 1;
        bf16_t* Oh = z ? Ok_h : Oq_h;
        bf16_t* Ol = z ? Ok_l : Oq_l;
        #pragma unroll
        for (int j = 0; j < 4; ++j) {
          const int gm = gm0 + j;
          const float t = acc[m][n][j];
          const float other = __shfl_xor(t, 1, 64);   // partner column d^1
          const int pos = tokpos[gm];
          const f32x2 cs2 = *(const f32x2*)&ropeT[((size_t)pos << 6) + ((d >> 1) << 1)];
          const float r = odd ? (other * cs2[1] + t * cs2[0])
                              : (t * cs2[0] - other * cs2[1]);
          const bf16_t hb = (bf16_t)r;
          const int b = gm >> 11, s = gm & 2047;
          const size_t oi = (((size_t)b * 16 + h) * 2048 + s) * 64 + d;
          Oh[oi] = hb;
          Ol[oi] = (bf16_t)(r - (float)hb);
        }
      }
    }
  }
}

// ------------- O projection GEMM (bf16 A, fp32 out), m97 single-buffer -------------
__global__ __launch_bounds__(256, 4) void gemm_o(
    const bf16_t* __restrict__ Ag, const bf16_t* __restrict__ Wg,
    float* __restrict__ Of)
{
  __shared__ __align__(16) bf16_t sA[128 * 64];
  __shared__ __align__(16) bf16_t sB[128 * 64];

  const int tid = threadIdx.x;
  const int lane = tid & 63, wv = tid >> 6;
  const int wr = wv >> 1, wc = wv & 1;
  const int la = lane & 15, lb = lane >> 4;
  const int row0 = blockIdx.x * 128, col0 = blockIdx.y * 128;

  const int srow = wv * 32 + (lane >> 3);
  const int schk = lane & 7;

  f32x4 acc[4][4] = {};

  for (int t = 0; t < 16; ++t) {
    const int k0 = t << 6;
    __syncthreads();
    #pragma unroll
    for (int i = 0; i < 4; ++i) {
      const int r = srow + i * 8;
      const int cs_ = (schk ^ (r & 7)) * 8;
      __builtin_amdgcn_global_load_lds(
          (gaddr_t)(Ag + (size_t)(row0 + r) * 1024 + k0 + cs_),
          (saddr_t)(sA + wv * 2048 + i * 512), 16, 0, 0);
      __builtin_amdgcn_global_load_lds(
          (gaddr_t)(Wg + (size_t)(col0 + r) * 1024 + k0 + cs_),
          (saddr_t)(sB + wv * 2048 + i * 512), 16, 0, 0);
    }
    __syncthreads();
    #pragma unroll
    for (int ks = 0; ks < 2; ++ks) {
      bf16x8 af[4];
      #pragma unroll
      for (int m = 0; m < 4; ++m) {
        const int r = wr * 64 + m * 16 + la;
        af[m] = *(const bf16x8*)&sA[r * 64 + (((ks * 4 + lb) ^ (la & 7)) * 8)];
      }
      #pragma unroll
      for (int n = 0; n < 4; ++n) {
        const int r = wc * 64 + n * 16 + la;
        const bf16x8 bfr = *(const bf16x8*)&sB[r * 64 + (((ks * 4 + lb) ^ (la & 7)) * 8)];
        #pragma unroll
        for (int m = 0; m < 4; ++m)
          acc[m][n] = __builtin_amdgcn_mfma_f32_16x16x32_bf16(af[m], bfr, acc[m][n], 0, 0, 0);
      }
    }
  }

  #pragma unroll
  for (int n = 0; n < 4; ++n) {
    const int gn = col0 + wc * 64 + n * 16 + la;
    #pragma unroll
    for (int m = 0; m < 4; ++m) {
      const int gm0 = row0 + wr * 64 + m * 16 + lb * 4;
      #pragma unroll
      for (int j = 0; j < 4; ++j)
        Of[(size_t)(gm0 + j) * 1024 + gn] = acc[m][n][j];
    }
  }
}

// XOR swizzle for 64-elem-wide bf16 LDS tiles (row = 128B).
__device__ __forceinline__ int SW(int e) { return e ^ (((e >> 6) & 7) << 3); }

// Flash attention, causal, split-bf16 QK^T, swapped operands (R4 structure).
// 512 persistent blocks x 512 threads; paired-qb (uniform 34 tiles/block).
__global__ __launch_bounds__(512, 4) void attn_kernel(
    const bf16_t* __restrict__ Qhi, const bf16_t* __restrict__ Qlo,
    const bf16_t* __restrict__ Khi, const bf16_t* __restrict__ Klo,
    const bf16_t* __restrict__ Vt, bf16_t* __restrict__ O)
{
  // [buf][ Kh(4096) | Kl(4096) | Vt(4096) ]
  __shared__ __align__(16) bf16_t sKV[2][3 * 4096];
  __shared__ __align__(16) bf16_t sP[8 * 1024];   // per-wave [q=la][kv], la-swizzled

  // XCD-aware remap: 512 blocks = 64 bh x 8 qb-pairs
  const int linear = (int)blockIdx.x;
  const int xcd = linear & 7;
  const int pos = linear >> 3;            // 0..63
  const int bh  = xcd * 8 + (pos >> 3);   // [0,64)
  const int p   = pos & 7;                // qb pair index
  const int b = bh >> 4, h = bh & 15;

  const size_t base = (size_t)bh * 2048 * 64;
  const bf16_t* Qh_ = Qhi + base;
  const bf16_t* Ql_ = Qlo + base;
  const bf16_t* Kh_ = Khi + base;
  const bf16_t* Kl_ = Klo + base;
  const bf16_t* Vt_ = Vt + base;    // [64 d][2048 s]

  const int tid = threadIdx.x, wv = tid >> 6, lane = tid & 63;
  const int la = lane & 15, lb = lane >> 4;

  // staging geometry (per thread, 3 x 16B): covers 24KB over 512 threads
  const int sr   = wv * 8 + (lane >> 3);        // tile row 0..63
  const int scsw = (lane & 7) ^ (sr & 7);       // inverse-swizzled 16B chunk
  const int ssrc = sr * 64 + scsw * 8;          // K source elem offset in tile
  const int se0  = wv * 512;                    // wave-uniform LDS chunk base
  const int psw  = (la & 7) << 3;               // sP swizzle key (kv bits 3..5)

  auto STAGE = [&](int kvb, int buf) {
    const int kv0 = kvb * 64;
    bf16_t* dst = &sKV[buf][0];
    __builtin_amdgcn_global_load_lds((gaddr_t)(Kh_ + (size_t)kv0 * 64 + ssrc),
                                     (saddr_t)(dst + se0), 16, 0, 0);
    __builtin_amdgcn_global_load_lds((gaddr_t)(Kl_ + (size_t)kv0 * 64 + ssrc),
                                     (saddr_t)(dst + 4096 + se0), 16, 0, 0);
    __builtin_amdgcn_global_load_lds((gaddr_t)(Vt_ + (size_t)sr * 2048 + kv0 + scsw * 8),
                                     (saddr_t)(dst + 8192 + se0), 16, 0, 0);
  };

  for (int half = 0; half < 2; ++half) {
    const int qb = half ? p : 15 - p;
    const int q = qb * 128 + wv * 16 + la;   // this lane's q row (global)
    bf16x8 qh[2], ql[2];
    #pragma unroll
    for (int kf = 0; kf < 2; ++kf) {
      qh[kf] = *(const bf16x8*)&Qh_[(size_t)q * 64 + kf * 32 + lb * 8];
      ql[kf] = *(const bf16x8*)&Ql_[(size_t)q * 64 + kf * 32 + lb * 8];
    }

    f32x4 oacc[4] = {};       // oacc[nf][j] = O^T[d = nf*16+lb*4+j][q = la]
    float m = -1e30f, l = 0.f;
    const int nt = 2 * qb + 2;

    STAGE(0, 0);
    __syncthreads();

    for (int kvb = 0; kvb < nt; ++kvb) {
      const int kv0 = kvb * 64;
      if (kvb + 1 < nt) STAGE(kvb + 1, (kvb + 1) & 1);

      const bf16_t* sKh = &sKV[kvb & 1][0];
      const bf16_t* sKl = sKh + 4096;
      const bf16_t* sVt = sKh + 8192;

      // S^T = K Q^T (3-term split): sacc[nf][j] at kv = kv0+nf*16+lb*4+j
      f32x4 sacc[4] = {};
      __builtin_amdgcn_s_setprio(1);
      #pragma unroll
      for (int nf = 0; nf < 4; ++nf) {
        #pragma unroll
        for (int kf = 0; kf < 2; ++kf) {
          const int rr = SW((nf * 16 + la) * 64 + kf * 32 + lb * 8);
          const bf16x8 kh = *(const bf16x8*)&sKh[rr];
          const bf16x8 kl = *(const bf16x8*)&sKl[rr];
          sacc[nf] = __builtin_amdgcn_mfma_f32_16x16x32_bf16(kh, qh[kf], sacc[nf], 0, 0, 0);
          sacc[nf] = __builtin_amdgcn_mfma_f32_16x16x32_bf16(kl, qh[kf], sacc[nf], 0, 0, 0);
          sacc[nf] = __builtin_amdgcn_mfma_f32_16x16x32_bf16(kh, ql[kf], sacc[nf], 0, 0, 0);
        }
      }
      __builtin_amdgcn_s_setprio(0);

      // mask + scale (mask only possibly-diagonal tiles: kvb >= 2*qb)
      if (kvb >= 2 * qb) {
        #pragma unroll
        for (int nf = 0; nf < 4; ++nf)
          #pragma unroll
          for (int j = 0; j < 4; ++j) {
            const int kvi = kv0 + nf * 16 + lb * 4 + j;
            sacc[nf][j] = (kvi <= q) ? sacc[nf][j] * 0.125f : -1e30f;
          }
      } else {
        #pragma unroll
        for (int nf = 0; nf < 4; ++nf)
          #pragma unroll
          for (int j = 0; j < 4; ++j) sacc[nf][j] *= 0.125f;
      }

      // row softmax: in-lane 16, then combine lb groups (lanes ^16, ^32)
      float red = sacc[0][0];
      #pragma unroll
      for (int nf = 0; nf < 4; ++nf)
        #pragma unroll
        for (int j = 0; j < 4; ++j) red = fmaxf(red, sacc[nf][j]);
      red = fmaxf(red, __shfl_xor(red, 16, 64));
      red = fmaxf(red, __shfl_xor(red, 32, 64));

      // defer-max (T13): only rescale when the max grew by more than THR=8
      const float mn = fmaxf(m, red);
      if (!__all(mn - m <= 8.0f)) {
        const float sf = __expf(m - mn);
        m = mn;
        l *= sf;
        #pragma unroll
        for (int nf = 0; nf < 4; ++nf)
          #pragma unroll
          for (int j = 0; j < 4; ++j) oacc[nf][j] *= sf;
      }

      float rs = 0.f;
      #pragma unroll
      for (int nf = 0; nf < 4; ++nf)
        #pragma unroll
        for (int j = 0; j < 4; ++j) {
          const float pj = __expf(sacc[nf][j] - m);
          sacc[nf][j] = pj;
          rs += pj;
        }
      rs += __shfl_xor(rs, 16, 64);
      rs += __shfl_xor(rs, 32, 64);
      l += rs;

      // P -> LDS: packed b64 per nf (4 consecutive kv), la-keyed swizzle
      #pragma unroll
      for (int nf = 0; nf < 4; ++nf) {
        bf16x4 pv;
        #pragma unroll
        for (int j = 0; j < 4; ++j) pv[j] = (bf16_t)sacc[nf][j];
        *(bf16x4*)&sP[wv * 1024 + la * 64 + ((nf * 16 + lb * 4) ^ psw)] = pv;
      }

      // O^T += V^T P^T : mfma(A=Vt rows d, B=P rows q)
      __builtin_amdgcn_s_setprio(1);
      #pragma unroll
      for (int ks = 0; ks < 2; ++ks) {
        const bf16x8 pa = *(const bf16x8*)&sP[wv * 1024 + la * 64 + ((ks * 32 + lb * 8) ^ psw)];
        #pragma unroll
        for (int nf = 0; nf < 4; ++nf) {
          const bf16x8 vb2 = *(const bf16x8*)&sVt[SW((nf * 16 + la) * 64 + ks * 32 + lb * 8)];
          oacc[nf] = __builtin_amdgcn_mfma_f32_16x16x32_bf16(vb2, pa, oacc[nf], 0, 0, 0);
        }
      }
      __builtin_amdgcn_s_setprio(0);

      __syncthreads();   // drains prefetch (vmcnt) + guards buffer overwrite
    }

    // epilogue: O[b,s,h,d] bf16, packed b64 (4 consecutive d per nf)
    const float inv_l = 1.0f / l;
    #pragma unroll
    for (int nf = 0; nf < 4; ++nf) {
      bf16x4 ov;
      #pragma unroll
      for (int j = 0; j < 4; ++j) ov[j] = (bf16_t)(oacc[nf][j] * inv_l);
      const int d0 = nf * 16 + lb * 4;
      *(bf16x4*)&O[(((size_t)b * 2048 + q) * 16 + h) * 64 + d0] = ov;
    }
  }
}

extern "C" void kernel_launch(void* const* d_in, const int* in_sizes, int n_in,
                              void* d_out, int out_size, void* d_ws, size_t ws_size,
                              hipStream_t stream)
{
  const float* x      = (const float*)d_in[0];
  const int*   tokpos = (const int*)d_in[1];
  const float* qw     = (const float*)d_in[2];
  const float* kw     = (const float*)d_in[3];
  const float* vw     = (const float*)d_in[4];
  const float* ow     = (const float*)d_in[5];
  float* out = (float*)d_out;

  const size_t E  = (size_t)4 * 16 * 2048 * 64;  // 8388608 elems per activation
  const size_t W1 = (size_t)1024 * 1024;         // weight elems
  bf16_t* base = (bf16_t*)d_ws;
  bf16_t* Qhi = base;
  bf16_t* Qlo = base + E;
  bf16_t* Khi = base + 2 * E;
  bf16_t* Klo = base + 3 * E;
  bf16_t* Vt  = base + 4 * E;        // [B,H,D,S]
  bf16_t* Xh  = base + 5 * E;
  bf16_t* Xl  = base + 6 * E;
  bf16_t* QWh = base + 7 * E;
  bf16_t* QWl = QWh + W1;
  bf16_t* KWh = QWh + 2 * W1;
  bf16_t* KWl = QWh + 3 * W1;
  bf16_t* VWh = QWh + 4 * W1;
  bf16_t* OWh = QWh + 5 * W1;
  float*  ropeT = (float*)(QWh + 6 * W1);        // 2048*64 floats
  bf16_t* O = Xh;                                 // alias: X dead before attn

  RopeTab tab;
  for (int i = 0; i < 32; ++i)
    tab.inv[i] = (float)pow(10000.0, -(double)i / 32.0);

  // fused pre-passes (splits + rope table)
  prep_k<<<12544, 256, 0, stream>>>(x, qw, kw, vw, ow, tab,
                                    Xh, Xl, QWh, QWl, KWh, KWl, VWh, OWh, ropeT);

  // Q and K projections: 256-sq 4-phase counted-vmcnt pipeline
  gemm_qk256<<<dim3(32, 4, 2), 512, 0, stream>>>(
      Xh, Xl, QWh, QWl, KWh, KWl, tokpos, ropeT, Qhi, Qlo, Khi, Klo);
  // V projection on the proven 128-sq kernel (zbase=2)
  gemm_qkv<<<dim3(64, 8, 1), 256, 0, stream>>>(
      Xh, Xl, QWh, QWl, KWh, KWl, VWh, tokpos, ropeT,
      Qhi, Qlo, Khi, Klo, Vt, 2);
  // attention: 512 persistent blocks x 512 threads
  attn_kernel<<<512, 512, 0, stream>>>(Qhi, Qlo, Khi, Klo, Vt, O);
  // output projection -> fp32 d_out
  gemm_o<<<dim3(64, 8), 256, 0, stream>>>(O, OWh, out);
}

// Round 11
// 268.260 us; speedup vs baseline: 1.0774x; 1.0774x over previous
//
#include <hip/hip_runtime.h>
#include <cmath>

// MHA fused forward, MI355X gfx950.
// R10: abandon 256-sq pipeline (R8/R9 both hit the documented 2-phase
//      ceiling ~640 TF; the fine m201 schedule didn't reproduce at HIP
//      level here). Back to the proven 884 TF 128-sq m97 structure, and
//      recover time from SCHEDULING GEOMETRY:
//      - Q/K: one uniform 1024-block launch (48 steps, exactly 1 round @4/CU)
//      - V:   BM=64 tiles -> 1024 blocks x 16 light steps (1 full round,
//             was 512 blocks on a half-empty machine)
//      - O:   BM=64 tiles -> 1024 blocks (4/CU TLP, was 2/CU)
// attn (paired-qb persistent) / prep unchanged from R7.
// Numerics: split-bf16 hi/lo 3-term for Q/K projections and QK^T.

typedef __bf16 bf16_t;
typedef __bf16 bf16x2 __attribute__((ext_vector_type(2)));
typedef __bf16 bf16x4 __attribute__((ext_vector_type(4)));
typedef __bf16 bf16x8 __attribute__((ext_vector_type(8)));
typedef float f32x2 __attribute__((ext_vector_type(2)));
typedef float f32x4 __attribute__((ext_vector_type(4)));
typedef unsigned int u32;
typedef const __attribute__((address_space(1))) u32* gaddr_t;
typedef __attribute__((address_space(3))) u32* saddr_t;

struct RopeTab { float inv[32]; };

// ---------------- fused pre-pass ----------------
__device__ __forceinline__ void split4(const float* __restrict__ in,
                                       bf16_t* __restrict__ hi,
                                       bf16_t* __restrict__ lo, bool LO,
                                       int blk, int tid)
{
  const int i = blk * 256 + tid;
  const f32x4 u = *(const f32x4*)(in + (size_t)i * 4);
  bf16x4 h, l;
  #pragma unroll
  for (int j = 0; j < 4; ++j) {
    const bf16_t hb = (bf16_t)u[j];
    h[j] = hb;
    if (LO) l[j] = (bf16_t)(u[j] - (float)hb);
  }
  *(bf16x4*)(hi + (size_t)i * 4) = h;
  if (LO) *(bf16x4*)(lo + (size_t)i * 4) = l;
}

__global__ __launch_bounds__(256) void prep_k(
    const float* __restrict__ x,  const float* __restrict__ qw,
    const float* __restrict__ kw, const float* __restrict__ vw,
    const float* __restrict__ ow, RopeTab tab,
    bf16_t* __restrict__ Xh,  bf16_t* __restrict__ Xl,
    bf16_t* __restrict__ QWh, bf16_t* __restrict__ QWl,
    bf16_t* __restrict__ KWh, bf16_t* __restrict__ KWl,
    bf16_t* __restrict__ VWh, bf16_t* __restrict__ OWh,
    float* __restrict__ ropeT)
{
  const int bid = blockIdx.x, tid = threadIdx.x;
  if (bid < 8192)       split4(x,  Xh,  Xl,  true,  bid,         tid);
  else if (bid < 9216)  split4(qw, QWh, QWl, true,  bid - 8192,  tid);
  else if (bid < 10240) split4(kw, KWh, KWl, true,  bid - 9216,  tid);
  else if (bid < 11264) split4(vw, VWh, nullptr, false, bid - 10240, tid);
  else if (bid < 12288) split4(ow, OWh, nullptr, false, bid - 11264, tid);
  else {
    const int i = (bid - 12288) * 256 + tid;   // 2048*32 entries
    const int p = i >> 5, d2 = i & 31;
    float sn, cs;
    sincosf((float)p * tab.inv[d2], &sn, &cs);
    ropeT[(size_t)i * 2]     = cs;
    ropeT[(size_t)i * 2 + 1] = sn;
  }
}

// ------------- Q/K projection GEMM (B^T), m97 single-buffer 128x128 -------------
// z=0: Q, z=1: K. K_eff=3072 (segments hh, hl, lh). RoPE epilogue -> hi/lo out.
__global__ __launch_bounds__(256, 4) void gemm_qk(
    const bf16_t* __restrict__ Xh, const bf16_t* __restrict__ Xl,
    const bf16_t* __restrict__ QWh, const bf16_t* __restrict__ QWl,
    const bf16_t* __restrict__ KWh, const bf16_t* __restrict__ KWl,
    const int* __restrict__ tokpos, const float* __restrict__ ropeT,
    bf16_t* __restrict__ Oq_h, bf16_t* __restrict__ Oq_l,
    bf16_t* __restrict__ Ok_h, bf16_t* __restrict__ Ok_l)
{
  __shared__ __align__(16) bf16_t sA[128 * 64];
  __shared__ __align__(16) bf16_t sB[128 * 64];

  const int tid = threadIdx.x;
  const int lane = tid & 63, wv = tid >> 6;
  const int wr = wv >> 1, wc = wv & 1;
  const int la = lane & 15, lb = lane >> 4;
  const int row0 = blockIdx.x * 128, col0 = blockIdx.y * 128;
  const int z = blockIdx.z;

  const bf16_t* Wh = z ? KWh : QWh;
  const bf16_t* Wl = z ? KWl : QWl;

  const int srow = wv * 32 + (lane >> 3);   // + i*8
  const int schk = lane & 7;                // physical 16B chunk within row

  f32x4 acc[4][4] = {};

  for (int t = 0; t < 48; ++t) {
    const int seg = t >> 4;
    const int k0 = (t & 15) << 6;
    const bf16_t* Ap = (seg == 2) ? Xl : Xh;
    const bf16_t* Wp = (seg == 1) ? Wl : Wh;
    __syncthreads();
    #pragma unroll
    for (int i = 0; i < 4; ++i) {
      const int r = srow + i * 8;
      const int cs_ = (schk ^ (r & 7)) * 8;       // inverse-swizzled source col
      __builtin_amdgcn_global_load_lds(
          (gaddr_t)(Ap + (size_t)(row0 + r) * 1024 + k0 + cs_),
          (saddr_t)(sA + wv * 2048 + i * 512), 16, 0, 0);
      __builtin_amdgcn_global_load_lds(
          (gaddr_t)(Wp + (size_t)(col0 + r) * 1024 + k0 + cs_),
          (saddr_t)(sB + wv * 2048 + i * 512), 16, 0, 0);
    }
    __syncthreads();

    #pragma unroll
    for (int ks = 0; ks < 2; ++ks) {
      bf16x8 af[4];
      #pragma unroll
      for (int m = 0; m < 4; ++m) {
        const int r = wr * 64 + m * 16 + la;
        af[m] = *(const bf16x8*)&sA[r * 64 + (((ks * 4 + lb) ^ (la & 7)) * 8)];
      }
      #pragma unroll
      for (int n = 0; n < 4; ++n) {
        const int r = wc * 64 + n * 16 + la;
        const bf16x8 bfr = *(const bf16x8*)&sB[r * 64 + (((ks * 4 + lb) ^ (la & 7)) * 8)];
        #pragma unroll
        for (int m = 0; m < 4; ++m)
          acc[m][n] = __builtin_amdgcn_mfma_f32_16x16x32_bf16(af[m], bfr, acc[m][n], 0, 0, 0);
      }
    }
  }

  // ---- epilogue: RoPE via table -> hi/lo bf16 [B,H,S,D] ----
  bf16_t* Oh = z ? Ok_h : Oq_h;
  bf16_t* Ol = z ? Ok_l : Oq_l;
  #pragma unroll
  for (int n = 0; n < 4; ++n) {
    const int gn = col0 + wc * 64 + n * 16 + la;
    const int d = gn & 63, h = gn >> 6;
    const bool odd = d & 1;
    #pragma unroll
    for (int m = 0; m < 4; ++m) {
      const int gm0 = row0 + wr * 64 + m * 16 + lb * 4;
      #pragma unroll
      for (int j = 0; j < 4; ++j) {
        const int gm = gm0 + j;
        const float t = acc[m][n][j];
        const float other = __shfl_xor(t, 1, 64);   // partner column d^1
        const int pos = tokpos[gm];
        const f32x2 cs2 = *(const f32x2*)&ropeT[((size_t)pos << 6) + ((d >> 1) << 1)];
        const float r = odd ? (other * cs2[1] + t * cs2[0])
                            : (t * cs2[0] - other * cs2[1]);
        const bf16_t hb = (bf16_t)r;
        const int b = gm >> 11, s = gm & 2047;
        const size_t oi = (((size_t)b * 16 + h) * 2048 + s) * 64 + d;
        Oh[oi] = hb;
        Ol[oi] = (bf16_t)(r - (float)hb);
      }
    }
  }
}

// ------------- V projection GEMM: 64x128 tile -> 1024 blocks (1 full round) ---
// out bf16 transposed [B,H,D,S] (packed 8B stores).
__global__ __launch_bounds__(256, 4) void gemm_v64(
    const bf16_t* __restrict__ Ag, const bf16_t* __restrict__ Wg,
    bf16_t* __restrict__ Vt)
{
  __shared__ __align__(16) bf16_t sA[64 * 64];    // 8 KB
  __shared__ __align__(16) bf16_t sB[128 * 64];   // 16 KB

  const int tid = threadIdx.x;
  const int lane = tid & 63, wv = tid >> 6;
  const int la = lane & 15, lb = lane >> 4;
  const int row0 = blockIdx.x * 64, col0 = blockIdx.y * 128;

  f32x4 acc[4][2] = {};   // rows m*16 (64), cols wv*32 + n*16 (32)

  for (int t = 0; t < 16; ++t) {
    const int k0 = t << 6;
    __syncthreads();
    // stage A: 64x64 (2 chunks/thread), B: 128x64 (4 chunks/thread)
    #pragma unroll
    for (int i = 0; i < 2; ++i) {
      const int c = i * 256 + tid;                 // 16B-chunk id in tile
      const int r = c >> 3;
      const int cs_ = ((c & 7) ^ (r & 7)) * 8;
      __builtin_amdgcn_global_load_lds(
          (gaddr_t)(Ag + (size_t)(row0 + r) * 1024 + k0 + cs_),
          (saddr_t)(sA + (i * 4 + wv) * 512 + (lane & 63) * 8), 16, 0, 0);
    }
    #pragma unroll
    for (int i = 0; i < 4; ++i) {
      const int c = i * 256 + tid;
      const int r = c >> 3;
      const int cs_ = ((c & 7) ^ (r & 7)) * 8;
      __builtin_amdgcn_global_load_lds(
          (gaddr_t)(Wg + (size_t)(col0 + r) * 1024 + k0 + cs_),
          (saddr_t)(sB + (i * 4 + wv) * 512 + (lane & 63) * 8), 16, 0, 0);
    }
    __syncthreads();

    #pragma unroll
    for (int ks = 0; ks < 2; ++ks) {
      const int kcol = ((ks * 4 + lb) ^ (la & 7)) * 8;
      bf16x8 af[4];
      #pragma unroll
      for (int m = 0; m < 4; ++m)
        af[m] = *(const bf16x8*)&sA[(m * 16 + la) * 64 + kcol];
      #pragma unroll
      for (int n = 0; n < 2; ++n) {
        const bf16x8 bfr = *(const bf16x8*)&sB[(wv * 32 + n * 16 + la) * 64 + kcol];
        #pragma unroll
        for (int m = 0; m < 4; ++m)
          acc[m][n] = __builtin_amdgcn_mfma_f32_16x16x32_bf16(af[m], bfr, acc[m][n], 0, 0, 0);
      }
    }
  }

  // epilogue: V^T [B,H,D,S], packed 8B stores
  #pragma unroll
  for (int n = 0; n < 2; ++n) {
    const int gn = col0 + wv * 32 + n * 16 + la;
    const int h = gn >> 6, d = gn & 63;
    #pragma unroll
    for (int m = 0; m < 4; ++m) {
      const int gm0 = row0 + m * 16 + lb * 4;
      const int b = gm0 >> 11, s0 = gm0 & 2047;
      bf16x4 v;
      #pragma unroll
      for (int j = 0; j < 4; ++j) v[j] = (bf16_t)acc[m][n][j];
      *(bf16x4*)&Vt[(((size_t)b * 16 + h) * 64 + d) * 2048 + s0] = v;
    }
  }
}

// ------------- O projection GEMM: 64x128 tile, fp32 out, 1024 blocks ---------
__global__ __launch_bounds__(256, 4) void gemm_o64(
    const bf16_t* __restrict__ Ag, const bf16_t* __restrict__ Wg,
    float* __restrict__ Of)
{
  __shared__ __align__(16) bf16_t sA[64 * 64];
  __shared__ __align__(16) bf16_t sB[128 * 64];

  const int tid = threadIdx.x;
  const int lane = tid & 63, wv = tid >> 6;
  const int la = lane & 15, lb = lane >> 4;
  const int row0 = blockIdx.x * 64, col0 = blockIdx.y * 128;

  f32x4 acc[4][2] = {};

  for (int t = 0; t < 16; ++t) {
    const int k0 = t << 6;
    __syncthreads();
    #pragma unroll
    for (int i = 0; i < 2; ++i) {
      const int c = i * 256 + tid;
      const int r = c >> 3;
      const int cs_ = ((c & 7) ^ (r & 7)) * 8;
      __builtin_amdgcn_global_load_lds(
          (gaddr_t)(Ag + (size_t)(row0 + r) * 1024 + k0 + cs_),
          (saddr_t)(sA + (i * 4 + wv) * 512 + (lane & 63) * 8), 16, 0, 0);
    }
    #pragma unroll
    for (int i = 0; i < 4; ++i) {
      const int c = i * 256 + tid;
      const int r = c >> 3;
      const int cs_ = ((c & 7) ^ (r & 7)) * 8;
      __builtin_amdgcn_global_load_lds(
          (gaddr_t)(Wg + (size_t)(col0 + r) * 1024 + k0 + cs_),
          (saddr_t)(sB + (i * 4 + wv) * 512 + (lane & 63) * 8), 16, 0, 0);
    }
    __syncthreads();

    #pragma unroll
    for (int ks = 0; ks < 2; ++ks) {
      const int kcol = ((ks * 4 + lb) ^ (la & 7)) * 8;
      bf16x8 af[4];
      #pragma unroll
      for (int m = 0; m < 4; ++m)
        af[m] = *(const bf16x8*)&sA[(m * 16 + la) * 64 + kcol];
      #pragma unroll
      for (int n = 0; n < 2; ++n) {
        const bf16x8 bfr = *(const bf16x8*)&sB[(wv * 32 + n * 16 + la) * 64 + kcol];
        #pragma unroll
        for (int m = 0; m < 4; ++m)
          acc[m][n] = __builtin_amdgcn_mfma_f32_16x16x32_bf16(af[m], bfr, acc[m][n], 0, 0, 0);
      }
    }
  }

  #pragma unroll
  for (int n = 0; n < 2; ++n) {
    const int gn = col0 + wv * 32 + n * 16 + la;
    #pragma unroll
    for (int m = 0; m < 4; ++m) {
      const int gm0 = row0 + m * 16 + lb * 4;
      #pragma unroll
      for (int j = 0; j < 4; ++j)
        Of[(size_t)(gm0 + j) * 1024 + gn] = acc[m][n][j];
    }
  }
}

// XOR swizzle for 64-elem-wide bf16 LDS tiles (row = 128B).
__device__ __forceinline__ int SW(int e) { return e ^ (((e >> 6) & 7) << 3); }

// Flash attention, causal, split-bf16 QK^T, swapped operands (R4 structure).
// 512 persistent blocks x 512 threads; paired-qb (uniform 34 tiles/block).
__global__ __launch_bounds__(512, 4) void attn_kernel(
    const bf16_t* __restrict__ Qhi, const bf16_t* __restrict__ Qlo,
    const bf16_t* __restrict__ Khi, const bf16_t* __restrict__ Klo,
    const bf16_t* __restrict__ Vt, bf16_t* __restrict__ O)
{
  // [buf][ Kh(4096) | Kl(4096) | Vt(4096) ]
  __shared__ __align__(16) bf16_t sKV[2][3 * 4096];
  __shared__ __align__(16) bf16_t sP[8 * 1024];   // per-wave [q=la][kv], la-swizzled

  // XCD-aware remap: 512 blocks = 64 bh x 8 qb-pairs
  const int linear = (int)blockIdx.x;
  const int xcd = linear & 7;
  const int pos = linear >> 3;            // 0..63
  const int bh  = xcd * 8 + (pos >> 3);   // [0,64)
  const int p   = pos & 7;                // qb pair index
  const int b = bh >> 4, h = bh & 15;

  const size_t base = (size_t)bh * 2048 * 64;
  const bf16_t* Qh_ = Qhi + base;
  const bf16_t* Ql_ = Qlo + base;
  const bf16_t* Kh_ = Khi + base;
  const bf16_t* Kl_ = Klo + base;
  const bf16_t* Vt_ = Vt + base;    // [64 d][2048 s]

  const int tid = threadIdx.x, wv = tid >> 6, lane = tid & 63;
  const int la = lane & 15, lb = lane >> 4;

  // staging geometry (per thread, 3 x 16B): covers 24KB over 512 threads
  const int sr   = wv * 8 + (lane >> 3);        // tile row 0..63
  const int scsw = (lane & 7) ^ (sr & 7);       // inverse-swizzled 16B chunk
  const int ssrc = sr * 64 + scsw * 8;          // K source elem offset in tile
  const int se0  = wv * 512;                    // wave-uniform LDS chunk base
  const int psw  = (la & 7) << 3;               // sP swizzle key (kv bits 3..5)

  auto STAGE = [&](int kvb, int buf) {
    const int kv0 = kvb * 64;
    bf16_t* dst = &sKV[buf][0];
    __builtin_amdgcn_global_load_lds((gaddr_t)(Kh_ + (size_t)kv0 * 64 + ssrc),
                                     (saddr_t)(dst + se0), 16, 0, 0);
    __builtin_amdgcn_global_load_lds((gaddr_t)(Kl_ + (size_t)kv0 * 64 + ssrc),
                                     (saddr_t)(dst + 4096 + se0), 16, 0, 0);
    __builtin_amdgcn_global_load_lds((gaddr_t)(Vt_ + (size_t)sr * 2048 + kv0 + scsw * 8),
                                     (saddr_t)(dst + 8192 + se0), 16, 0, 0);
  };

  for (int half = 0; half < 2; ++half) {
    const int qb = half ? p : 15 - p;
    const int q = qb * 128 + wv * 16 + la;   // this lane's q row (global)
    bf16x8 qh[2], ql[2];
    #pragma unroll
    for (int kf = 0; kf < 2; ++kf) {
      qh[kf] = *(const bf16x8*)&Qh_[(size_t)q * 64 + kf * 32 + lb * 8];
      ql[kf] = *(const bf16x8*)&Ql_[(size_t)q * 64 + kf * 32 + lb * 8];
    }

    f32x4 oacc[4] = {};       // oacc[nf][j] = O^T[d = nf*16+lb*4+j][q = la]
    float m = -1e30f, l = 0.f;
    const int nt = 2 * qb + 2;

    STAGE(0, 0);
    __syncthreads();

    for (int kvb = 0; kvb < nt; ++kvb) {
      const int kv0 = kvb * 64;
      if (kvb + 1 < nt) STAGE(kvb + 1, (kvb + 1) & 1);

      const bf16_t* sKh = &sKV[kvb & 1][0];
      const bf16_t* sKl = sKh + 4096;
      const bf16_t* sVt = sKh + 8192;

      // S^T = K Q^T (3-term split): sacc[nf][j] at kv = kv0+nf*16+lb*4+j
      f32x4 sacc[4] = {};
      __builtin_amdgcn_s_setprio(1);
      #pragma unroll
      for (int nf = 0; nf < 4; ++nf) {
        #pragma unroll
        for (int kf = 0; kf < 2; ++kf) {
          const int rr = SW((nf * 16 + la) * 64 + kf * 32 + lb * 8);
          const bf16x8 kh = *(const bf16x8*)&sKh[rr];
          const bf16x8 kl = *(const bf16x8*)&sKl[rr];
          sacc[nf] = __builtin_amdgcn_mfma_f32_16x16x32_bf16(kh, qh[kf], sacc[nf], 0, 0, 0);
          sacc[nf] = __builtin_amdgcn_mfma_f32_16x16x32_bf16(kl, qh[kf], sacc[nf], 0, 0, 0);
          sacc[nf] = __builtin_amdgcn_mfma_f32_16x16x32_bf16(kh, ql[kf], sacc[nf], 0, 0, 0);
        }
      }
      __builtin_amdgcn_s_setprio(0);

      // mask + scale (mask only possibly-diagonal tiles: kvb >= 2*qb)
      if (kvb >= 2 * qb) {
        #pragma unroll
        for (int nf = 0; nf < 4; ++nf)
          #pragma unroll
          for (int j = 0; j < 4; ++j) {
            const int kvi = kv0 + nf * 16 + lb * 4 + j;
            sacc[nf][j] = (kvi <= q) ? sacc[nf][j] * 0.125f : -1e30f;
          }
      } else {
        #pragma unroll
        for (int nf = 0; nf < 4; ++nf)
          #pragma unroll
          for (int j = 0; j < 4; ++j) sacc[nf][j] *= 0.125f;
      }

      // row softmax: in-lane 16, then combine lb groups (lanes ^16, ^32)
      float red = sacc[0][0];
      #pragma unroll
      for (int nf = 0; nf < 4; ++nf)
        #pragma unroll
        for (int j = 0; j < 4; ++j) red = fmaxf(red, sacc[nf][j]);
      red = fmaxf(red, __shfl_xor(red, 16, 64));
      red = fmaxf(red, __shfl_xor(red, 32, 64));

      // defer-max (T13): only rescale when the max grew by more than THR=8
      const float mn = fmaxf(m, red);
      if (!__all(mn - m <= 8.0f)) {
        const float sf = __expf(m - mn);
        m = mn;
        l *= sf;
        #pragma unroll
        for (int nf = 0; nf < 4; ++nf)
          #pragma unroll
          for (int j = 0; j < 4; ++j) oacc[nf][j] *= sf;
      }

      float rs = 0.f;
      #pragma unroll
      for (int nf = 0; nf < 4; ++nf)
        #pragma unroll
        for (int j = 0; j < 4; ++j) {
          const float pj = __expf(sacc[nf][j] - m);
          sacc[nf][j] = pj;
          rs += pj;
        }
      rs += __shfl_xor(rs, 16, 64);
      rs += __shfl_xor(rs, 32, 64);
      l += rs;

      // P -> LDS: packed b64 per nf (4 consecutive kv), la-keyed swizzle
      #pragma unroll
      for (int nf = 0; nf < 4; ++nf) {
        bf16x4 pv;
        #pragma unroll
        for (int j = 0; j < 4; ++j) pv[j] = (bf16_t)sacc[nf][j];
        *(bf16x4*)&sP[wv * 1024 + la * 64 + ((nf * 16 + lb * 4) ^ psw)] = pv;
      }

      // O^T += V^T P^T : mfma(A=Vt rows d, B=P rows q)
      __builtin_amdgcn_s_setprio(1);
      #pragma unroll
      for (int ks = 0; ks < 2; ++ks) {
        const bf16x8 pa = *(const bf16x8*)&sP[wv * 1024 + la * 64 + ((ks * 32 + lb * 8) ^ psw)];
        #pragma unroll
        for (int nf = 0; nf < 4; ++nf) {
          const bf16x8 vb2 = *(const bf16x8*)&sVt[SW((nf * 16 + la) * 64 + ks * 32 + lb * 8)];
          oacc[nf] = __builtin_amdgcn_mfma_f32_16x16x32_bf16(vb2, pa, oacc[nf], 0, 0, 0);
        }
      }
      __builtin_amdgcn_s_setprio(0);

      __syncthreads();   // drains prefetch (vmcnt) + guards buffer overwrite
    }

    // epilogue: O[b,s,h,d] bf16, packed b64 (4 consecutive d per nf)
    const float inv_l = 1.0f / l;
    #pragma unroll
    for (int nf = 0; nf < 4; ++nf) {
      bf16x4 ov;
      #pragma unroll
      for (int j = 0; j < 4; ++j) ov[j] = (bf16_t)(oacc[nf][j] * inv_l);
      const int d0 = nf * 16 + lb * 4;
      *(bf16x4*)&O[(((size_t)b * 2048 + q) * 16 + h) * 64 + d0] = ov;
    }
  }
}

extern "C" void kernel_launch(void* const* d_in, const int* in_sizes, int n_in,
                              void* d_out, int out_size, void* d_ws, size_t ws_size,
                              hipStream_t stream)
{
  const float* x      = (const float*)d_in[0];
  const int*   tokpos = (const int*)d_in[1];
  const float* qw     = (const float*)d_in[2];
  const float* kw     = (const float*)d_in[3];
  const float* vw     = (const float*)d_in[4];
  const float* ow     = (const float*)d_in[5];
  float* out = (float*)d_out;

  const size_t E  = (size_t)4 * 16 * 2048 * 64;  // 8388608 elems per activation
  const size_t W1 = (size_t)1024 * 1024;         // weight elems
  bf16_t* base = (bf16_t*)d_ws;
  bf16_t* Qhi = base;
  bf16_t* Qlo = base + E;
  bf16_t* Khi = base + 2 * E;
  bf16_t* Klo = base + 3 * E;
  bf16_t* Vt  = base + 4 * E;        // [B,H,D,S]
  bf16_t* Xh  = base + 5 * E;
  bf16_t* Xl  = base + 6 * E;
  bf16_t* QWh = base + 7 * E;
  bf16_t* QWl = QWh + W1;
  bf16_t* KWh = QWh + 2 * W1;
  bf16_t* KWl = QWh + 3 * W1;
  bf16_t* VWh = QWh + 4 * W1;
  bf16_t* OWh = QWh + 5 * W1;
  float*  ropeT = (float*)(QWh + 6 * W1);        // 2048*64 floats
  bf16_t* O = Xh;                                 // alias: X dead before attn

  RopeTab tab;
  for (int i = 0; i < 32; ++i)
    tab.inv[i] = (float)pow(10000.0, -(double)i / 32.0);

  // fused pre-passes (splits + rope table)
  prep_k<<<12544, 256, 0, stream>>>(x, qw, kw, vw, ow, tab,
                                    Xh, Xl, QWh, QWl, KWh, KWl, VWh, OWh, ropeT);

  // Q and K projections: 1024 uniform blocks (exactly one round @ 4/CU)
  gemm_qk<<<dim3(64, 8, 2), 256, 0, stream>>>(
      Xh, Xl, QWh, QWl, KWh, KWl, tokpos, ropeT, Qhi, Qlo, Khi, Klo);
  // V projection: 64x128 tiles -> 1024 blocks (one full round)
  gemm_v64<<<dim3(128, 8), 256, 0, stream>>>(Xh, VWh, Vt);
  // attention: 512 persistent blocks x 512 threads
  attn_kernel<<<512, 512, 0, stream>>>(Qhi, Qlo, Khi, Klo, Vt, O);
  // output projection: 64x128 tiles -> 1024 blocks, fp32 out
  gemm_o64<<<dim3(128, 8), 256, 0, stream>>>(O, OWh, out);
}

// Round 12
// 249.741 us; speedup vs baseline: 1.1573x; 1.0742x over previous
//
#include <hip/hip_runtime.h>
#include <cmath>

// MHA fused forward, MI355X gfx950.
// R11: revert to R7 config (241.7us known-good; R10's split launches lost
//      tail-backfill -- same-stream kernels serialize). One change: merged
//      shared-A Q+K GEMM (gemm_qkv2 z=0): 512-thread block stages {A,QW,KW}
//      (48KB) once and computes BOTH 128-sq outputs (waves 0-3 Q, 4-7 K).
//      Staged bytes per MFMA drop 8->3 chunks/output; per-wave profile
//      (32 MFMA/step, 64-VGPR acc) identical to the proven R7 wave.
//      V rides as z=1 light blocks in the SAME dispatch (co-residency).
// attn (paired-qb persistent) / gemm_o / prep unchanged from R7.
// Numerics: split-bf16 hi/lo 3-term for Q/K projections and QK^T.

typedef __bf16 bf16_t;
typedef __bf16 bf16x2 __attribute__((ext_vector_type(2)));
typedef __bf16 bf16x4 __attribute__((ext_vector_type(4)));
typedef __bf16 bf16x8 __attribute__((ext_vector_type(8)));
typedef float f32x2 __attribute__((ext_vector_type(2)));
typedef float f32x4 __attribute__((ext_vector_type(4)));
typedef unsigned int u32;
typedef const __attribute__((address_space(1))) u32* gaddr_t;
typedef __attribute__((address_space(3))) u32* saddr_t;

struct RopeTab { float inv[32]; };

// ---------------- fused pre-pass ----------------
__device__ __forceinline__ void split4(const float* __restrict__ in,
                                       bf16_t* __restrict__ hi,
                                       bf16_t* __restrict__ lo, bool LO,
                                       int blk, int tid)
{
  const int i = blk * 256 + tid;
  const f32x4 u = *(const f32x4*)(in + (size_t)i * 4);
  bf16x4 h, l;
  #pragma unroll
  for (int j = 0; j < 4; ++j) {
    const bf16_t hb = (bf16_t)u[j];
    h[j] = hb;
    if (LO) l[j] = (bf16_t)(u[j] - (float)hb);
  }
  *(bf16x4*)(hi + (size_t)i * 4) = h;
  if (LO) *(bf16x4*)(lo + (size_t)i * 4) = l;
}

__global__ __launch_bounds__(256) void prep_k(
    const float* __restrict__ x,  const float* __restrict__ qw,
    const float* __restrict__ kw, const float* __restrict__ vw,
    const float* __restrict__ ow, RopeTab tab,
    bf16_t* __restrict__ Xh,  bf16_t* __restrict__ Xl,
    bf16_t* __restrict__ QWh, bf16_t* __restrict__ QWl,
    bf16_t* __restrict__ KWh, bf16_t* __restrict__ KWl,
    bf16_t* __restrict__ VWh, bf16_t* __restrict__ OWh,
    float* __restrict__ ropeT)
{
  const int bid = blockIdx.x, tid = threadIdx.x;
  if (bid < 8192)       split4(x,  Xh,  Xl,  true,  bid,         tid);
  else if (bid < 9216)  split4(qw, QWh, QWl, true,  bid - 8192,  tid);
  else if (bid < 10240) split4(kw, KWh, KWl, true,  bid - 9216,  tid);
  else if (bid < 11264) split4(vw, VWh, nullptr, false, bid - 10240, tid);
  else if (bid < 12288) split4(ow, OWh, nullptr, false, bid - 11264, tid);
  else {
    const int i = (bid - 12288) * 256 + tid;   // 2048*32 entries
    const int p = i >> 5, d2 = i & 31;
    float sn, cs;
    sincosf((float)p * tab.inv[d2], &sn, &cs);
    ropeT[(size_t)i * 2]     = cs;
    ropeT[(size_t)i * 2 + 1] = sn;
  }
}

// ===== merged QKV projection: 512 threads/block =====
// z=0: shared-A Q+K block. Stages A(128x64)+QW+KW (48KB) per K-step;
//      waves 0-3 compute Q 128x128, waves 4-7 compute K 128x128.
//      K_eff=3072 (segments hh, hl, lh); RoPE epilogue -> hi/lo out.
// z=1: V block. Stages A+VW; 8 waves over one 128x128 V tile, 16 steps;
//      out bf16 transposed [B,H,D,S].
__global__ __launch_bounds__(512, 4) void gemm_qkv2(
    const bf16_t* __restrict__ Xh, const bf16_t* __restrict__ Xl,
    const bf16_t* __restrict__ QWh, const bf16_t* __restrict__ QWl,
    const bf16_t* __restrict__ KWh, const bf16_t* __restrict__ KWl,
    const bf16_t* __restrict__ VWh,
    const int* __restrict__ tokpos, const float* __restrict__ ropeT,
    bf16_t* __restrict__ Oq_h, bf16_t* __restrict__ Oq_l,
    bf16_t* __restrict__ Ok_h, bf16_t* __restrict__ Ok_l,
    bf16_t* __restrict__ Vt)
{
  __shared__ __align__(16) bf16_t sA[128 * 64];    // 16 KB
  __shared__ __align__(16) bf16_t sW0[128 * 64];   // QW / VW
  __shared__ __align__(16) bf16_t sW1[128 * 64];   // KW (idle for V blocks)

  const int tid = threadIdx.x;              // 0..511
  const int lane = tid & 63, wv = tid >> 6; // 8 waves
  const int la = lane & 15, lb = lane >> 4;
  const int row0 = blockIdx.x * 128, col0 = blockIdx.y * 128;

  // staging: chunk c = i*512 + tid covers one 16B chunk of a 128x64 tile.
  // linear LDS dest (wave-uniform base + lane*16), inverse-swizzled source.
  const int c0 = tid, c1 = 512 + tid;
  const int r0 = c0 >> 3, r1 = c1 >> 3;
  const int cs0 = ((c0 & 7) ^ (r0 & 7)) * 8;
  const int cs1 = ((c1 & 7) ^ (r1 & 7)) * 8;
  const int db0 = wv * 512;                 // dest elem base, i=0
  const int db1 = 4096 + wv * 512;          // dest elem base, i=1

  if (blockIdx.z == 0) {
    // ---------------- merged Q+K ----------------
    const int grp = wv >> 2, wq = wv & 3;   // grp 0=Q, 1=K
    const int wr = wq >> 1, wc = wq & 1;
    f32x4 acc[4][4] = {};

    for (int t = 0; t < 48; ++t) {
      const int seg = t >> 4;
      const int k0 = (t & 15) << 6;
      const bf16_t* Ap = (seg == 2) ? Xl : Xh;
      const bf16_t* Qp = (seg == 1) ? QWl : QWh;
      const bf16_t* Kp = (seg == 1) ? KWl : KWh;
      __syncthreads();
      __builtin_amdgcn_global_load_lds(
          (gaddr_t)(Ap + (size_t)(row0 + r0) * 1024 + k0 + cs0), (saddr_t)(sA + db0), 16, 0, 0);
      __builtin_amdgcn_global_load_lds(
          (gaddr_t)(Ap + (size_t)(row0 + r1) * 1024 + k0 + cs1), (saddr_t)(sA + db1), 16, 0, 0);
      __builtin_amdgcn_global_load_lds(
          (gaddr_t)(Qp + (size_t)(col0 + r0) * 1024 + k0 + cs0), (saddr_t)(sW0 + db0), 16, 0, 0);
      __builtin_amdgcn_global_load_lds(
          (gaddr_t)(Qp + (size_t)(col0 + r1) * 1024 + k0 + cs1), (saddr_t)(sW0 + db1), 16, 0, 0);
      __builtin_amdgcn_global_load_lds(
          (gaddr_t)(Kp + (size_t)(col0 + r0) * 1024 + k0 + cs0), (saddr_t)(sW1 + db0), 16, 0, 0);
      __builtin_amdgcn_global_load_lds(
          (gaddr_t)(Kp + (size_t)(col0 + r1) * 1024 + k0 + cs1), (saddr_t)(sW1 + db1), 16, 0, 0);
      __syncthreads();

      const bf16_t* sW = grp ? sW1 : sW0;
      #pragma unroll
      for (int ks = 0; ks < 2; ++ks) {
        const int kcol = ((ks * 4 + lb) ^ (la & 7)) * 8;
        bf16x8 af[4];
        #pragma unroll
        for (int m = 0; m < 4; ++m)
          af[m] = *(const bf16x8*)&sA[(wr * 64 + m * 16 + la) * 64 + kcol];
        #pragma unroll
        for (int n = 0; n < 4; ++n) {
          const bf16x8 bfr = *(const bf16x8*)&sW[(wc * 64 + n * 16 + la) * 64 + kcol];
          #pragma unroll
          for (int m = 0; m < 4; ++m)
            acc[m][n] = __builtin_amdgcn_mfma_f32_16x16x32_bf16(af[m], bfr, acc[m][n], 0, 0, 0);
        }
      }
    }

    // epilogue: RoPE -> hi/lo bf16 [B,H,S,D]
    bf16_t* Oh = grp ? Ok_h : Oq_h;
    bf16_t* Ol = grp ? Ok_l : Oq_l;
    #pragma unroll
    for (int n = 0; n < 4; ++n) {
      const int gn = col0 + wc * 64 + n * 16 + la;
      const int d = gn & 63, h = gn >> 6;
      const bool odd = d & 1;
      #pragma unroll
      for (int m = 0; m < 4; ++m) {
        const int gm0 = row0 + wr * 64 + m * 16 + lb * 4;
        #pragma unroll
        for (int j = 0; j < 4; ++j) {
          const int gm = gm0 + j;
          const float t = acc[m][n][j];
          const float other = __shfl_xor(t, 1, 64);   // partner column d^1
          const int pos = tokpos[gm];
          const f32x2 cs2 = *(const f32x2*)&ropeT[((size_t)pos << 6) + ((d >> 1) << 1)];
          const float r = odd ? (other * cs2[1] + t * cs2[0])
                              : (t * cs2[0] - other * cs2[1]);
          const bf16_t hb = (bf16_t)r;
          const int b = gm >> 11, s = gm & 2047;
          const size_t oi = (((size_t)b * 16 + h) * 2048 + s) * 64 + d;
          Oh[oi] = hb;
          Ol[oi] = (bf16_t)(r - (float)hb);
        }
      }
    }
  } else {
    // ---------------- V projection ----------------
    const int wr = wv >> 2, wc = wv & 3;    // 2 (M) x 4 (N) over 128x128
    f32x4 acc[4][2] = {};

    for (int t = 0; t < 16; ++t) {
      const int k0 = t << 6;
      __syncthreads();
      __builtin_amdgcn_global_load_lds(
          (gaddr_t)(Xh + (size_t)(row0 + r0) * 1024 + k0 + cs0), (saddr_t)(sA + db0), 16, 0, 0);
      __builtin_amdgcn_global_load_lds(
          (gaddr_t)(Xh + (size_t)(row0 + r1) * 1024 + k0 + cs1), (saddr_t)(sA + db1), 16, 0, 0);
      __builtin_amdgcn_global_load_lds(
          (gaddr_t)(VWh + (size_t)(col0 + r0) * 1024 + k0 + cs0), (saddr_t)(sW0 + db0), 16, 0, 0);
      __builtin_amdgcn_global_load_lds(
          (gaddr_t)(VWh + (size_t)(col0 + r1) * 1024 + k0 + cs1), (saddr_t)(sW0 + db1), 16, 0, 0);
      __syncthreads();

      #pragma unroll
      for (int ks = 0; ks < 2; ++ks) {
        const int kcol = ((ks * 4 + lb) ^ (la & 7)) * 8;
        bf16x8 af[4];
        #pragma unroll
        for (int m = 0; m < 4; ++m)
          af[m] = *(const bf16x8*)&sA[(wr * 64 + m * 16 + la) * 64 + kcol];
        #pragma unroll
        for (int n = 0; n < 2; ++n) {
          const bf16x8 bfr = *(const bf16x8*)&sW0[(wc * 32 + n * 16 + la) * 64 + kcol];
          #pragma unroll
          for (int m = 0; m < 4; ++m)
            acc[m][n] = __builtin_amdgcn_mfma_f32_16x16x32_bf16(af[m], bfr, acc[m][n], 0, 0, 0);
        }
      }
    }

    // epilogue: V^T [B,H,D,S], packed 8B stores
    #pragma unroll
    for (int n = 0; n < 2; ++n) {
      const int gn = col0 + wc * 32 + n * 16 + la;
      const int h = gn >> 6, d = gn & 63;
      #pragma unroll
      for (int m = 0; m < 4; ++m) {
        const int gm0 = row0 + wr * 64 + m * 16 + lb * 4;
        const int b = gm0 >> 11, s0 = gm0 & 2047;
        bf16x4 v;
        #pragma unroll
        for (int j = 0; j < 4; ++j) v[j] = (bf16_t)acc[m][n][j];
        *(bf16x4*)&Vt[(((size_t)b * 16 + h) * 64 + d) * 2048 + s0] = v;
      }
    }
  }
}

// ------------- O projection GEMM (bf16 A, fp32 out), m97 single-buffer -------------
__global__ __launch_bounds__(256, 4) void gemm_o(
    const bf16_t* __restrict__ Ag, const bf16_t* __restrict__ Wg,
    float* __restrict__ Of)
{
  __shared__ __align__(16) bf16_t sA[128 * 64];
  __shared__ __align__(16) bf16_t sB[128 * 64];

  const int tid = threadIdx.x;
  const int lane = tid & 63, wv = tid >> 6;
  const int wr = wv >> 1, wc = wv & 1;
  const int la = lane & 15, lb = lane >> 4;
  const int row0 = blockIdx.x * 128, col0 = blockIdx.y * 128;

  const int srow = wv * 32 + (lane >> 3);
  const int schk = lane & 7;

  f32x4 acc[4][4] = {};

  for (int t = 0; t < 16; ++t) {
    const int k0 = t << 6;
    __syncthreads();
    #pragma unroll
    for (int i = 0; i < 4; ++i) {
      const int r = srow + i * 8;
      const int cs_ = (schk ^ (r & 7)) * 8;
      __builtin_amdgcn_global_load_lds(
          (gaddr_t)(Ag + (size_t)(row0 + r) * 1024 + k0 + cs_),
          (saddr_t)(sA + wv * 2048 + i * 512), 16, 0, 0);
      __builtin_amdgcn_global_load_lds(
          (gaddr_t)(Wg + (size_t)(col0 + r) * 1024 + k0 + cs_),
          (saddr_t)(sB + wv * 2048 + i * 512), 16, 0, 0);
    }
    __syncthreads();
    #pragma unroll
    for (int ks = 0; ks < 2; ++ks) {
      bf16x8 af[4];
      #pragma unroll
      for (int m = 0; m < 4; ++m) {
        const int r = wr * 64 + m * 16 + la;
        af[m] = *(const bf16x8*)&sA[r * 64 + (((ks * 4 + lb) ^ (la & 7)) * 8)];
      }
      #pragma unroll
      for (int n = 0; n < 4; ++n) {
        const int r = wc * 64 + n * 16 + la;
        const bf16x8 bfr = *(const bf16x8*)&sB[r * 64 + (((ks * 4 + lb) ^ (la & 7)) * 8)];
        #pragma unroll
        for (int m = 0; m < 4; ++m)
          acc[m][n] = __builtin_amdgcn_mfma_f32_16x16x32_bf16(af[m], bfr, acc[m][n], 0, 0, 0);
      }
    }
  }

  #pragma unroll
  for (int n = 0; n < 4; ++n) {
    const int gn = col0 + wc * 64 + n * 16 + la;
    #pragma unroll
    for (int m = 0; m < 4; ++m) {
      const int gm0 = row0 + wr * 64 + m * 16 + lb * 4;
      #pragma unroll
      for (int j = 0; j < 4; ++j)
        Of[(size_t)(gm0 + j) * 1024 + gn] = acc[m][n][j];
    }
  }
}

// XOR swizzle for 64-elem-wide bf16 LDS tiles (row = 128B).
__device__ __forceinline__ int SW(int e) { return e ^ (((e >> 6) & 7) << 3); }

// Flash attention, causal, split-bf16 QK^T, swapped operands (R4 structure).
// 512 persistent blocks x 512 threads; paired-qb (uniform 34 tiles/block).
__global__ __launch_bounds__(512, 4) void attn_kernel(
    const bf16_t* __restrict__ Qhi, const bf16_t* __restrict__ Qlo,
    const bf16_t* __restrict__ Khi, const bf16_t* __restrict__ Klo,
    const bf16_t* __restrict__ Vt, bf16_t* __restrict__ O)
{
  // [buf][ Kh(4096) | Kl(4096) | Vt(4096) ]
  __shared__ __align__(16) bf16_t sKV[2][3 * 4096];
  __shared__ __align__(16) bf16_t sP[8 * 1024];   // per-wave [q=la][kv], la-swizzled

  // XCD-aware remap: 512 blocks = 64 bh x 8 qb-pairs
  const int linear = (int)blockIdx.x;
  const int xcd = linear & 7;
  const int pos = linear >> 3;            // 0..63
  const int bh  = xcd * 8 + (pos >> 3);   // [0,64)
  const int p   = pos & 7;                // qb pair index
  const int b = bh >> 4, h = bh & 15;

  const size_t base = (size_t)bh * 2048 * 64;
  const bf16_t* Qh_ = Qhi + base;
  const bf16_t* Ql_ = Qlo + base;
  const bf16_t* Kh_ = Khi + base;
  const bf16_t* Kl_ = Klo + base;
  const bf16_t* Vt_ = Vt + base;    // [64 d][2048 s]

  const int tid = threadIdx.x, wv = tid >> 6, lane = tid & 63;
  const int la = lane & 15, lb = lane >> 4;

  // staging geometry (per thread, 3 x 16B): covers 24KB over 512 threads
  const int sr   = wv * 8 + (lane >> 3);        // tile row 0..63
  const int scsw = (lane & 7) ^ (sr & 7);       // inverse-swizzled 16B chunk
  const int ssrc = sr * 64 + scsw * 8;          // K source elem offset in tile
  const int se0  = wv * 512;                    // wave-uniform LDS chunk base
  const int psw  = (la & 7) << 3;               // sP swizzle key (kv bits 3..5)

  auto STAGE = [&](int kvb, int buf) {
    const int kv0 = kvb * 64;
    bf16_t* dst = &sKV[buf][0];
    __builtin_amdgcn_global_load_lds((gaddr_t)(Kh_ + (size_t)kv0 * 64 + ssrc),
                                     (saddr_t)(dst + se0), 16, 0, 0);
    __builtin_amdgcn_global_load_lds((gaddr_t)(Kl_ + (size_t)kv0 * 64 + ssrc),
                                     (saddr_t)(dst + 4096 + se0), 16, 0, 0);
    __builtin_amdgcn_global_load_lds((gaddr_t)(Vt_ + (size_t)sr * 2048 + kv0 + scsw * 8),
                                     (saddr_t)(dst + 8192 + se0), 16, 0, 0);
  };

  for (int half = 0; half < 2; ++half) {
    const int qb = half ? p : 15 - p;
    const int q = qb * 128 + wv * 16 + la;   // this lane's q row (global)
    bf16x8 qh[2], ql[2];
    #pragma unroll
    for (int kf = 0; kf < 2; ++kf) {
      qh[kf] = *(const bf16x8*)&Qh_[(size_t)q * 64 + kf * 32 + lb * 8];
      ql[kf] = *(const bf16x8*)&Ql_[(size_t)q * 64 + kf * 32 + lb * 8];
    }

    f32x4 oacc[4] = {};       // oacc[nf][j] = O^T[d = nf*16+lb*4+j][q = la]
    float m = -1e30f, l = 0.f;
    const int nt = 2 * qb + 2;

    STAGE(0, 0);
    __syncthreads();

    for (int kvb = 0; kvb < nt; ++kvb) {
      const int kv0 = kvb * 64;
      if (kvb + 1 < nt) STAGE(kvb + 1, (kvb + 1) & 1);

      const bf16_t* sKh = &sKV[kvb & 1][0];
      const bf16_t* sKl = sKh + 4096;
      const bf16_t* sVt = sKh + 8192;

      // S^T = K Q^T (3-term split): sacc[nf][j] at kv = kv0+nf*16+lb*4+j
      f32x4 sacc[4] = {};
      __builtin_amdgcn_s_setprio(1);
      #pragma unroll
      for (int nf = 0; nf < 4; ++nf) {
        #pragma unroll
        for (int kf = 0; kf < 2; ++kf) {
          const int rr = SW((nf * 16 + la) * 64 + kf * 32 + lb * 8);
          const bf16x8 kh = *(const bf16x8*)&sKh[rr];
          const bf16x8 kl = *(const bf16x8*)&sKl[rr];
          sacc[nf] = __builtin_amdgcn_mfma_f32_16x16x32_bf16(kh, qh[kf], sacc[nf], 0, 0, 0);
          sacc[nf] = __builtin_amdgcn_mfma_f32_16x16x32_bf16(kl, qh[kf], sacc[nf], 0, 0, 0);
          sacc[nf] = __builtin_amdgcn_mfma_f32_16x16x32_bf16(kh, ql[kf], sacc[nf], 0, 0, 0);
        }
      }
      __builtin_amdgcn_s_setprio(0);

      // mask + scale (mask only possibly-diagonal tiles: kvb >= 2*qb)
      if (kvb >= 2 * qb) {
        #pragma unroll
        for (int nf = 0; nf < 4; ++nf)
          #pragma unroll
          for (int j = 0; j < 4; ++j) {
            const int kvi = kv0 + nf * 16 + lb * 4 + j;
            sacc[nf][j] = (kvi <= q) ? sacc[nf][j] * 0.125f : -1e30f;
          }
      } else {
        #pragma unroll
        for (int nf = 0; nf < 4; ++nf)
          #pragma unroll
          for (int j = 0; j < 4; ++j) sacc[nf][j] *= 0.125f;
      }

      // row softmax: in-lane 16, then combine lb groups (lanes ^16, ^32)
      float red = sacc[0][0];
      #pragma unroll
      for (int nf = 0; nf < 4; ++nf)
        #pragma unroll
        for (int j = 0; j < 4; ++j) red = fmaxf(red, sacc[nf][j]);
      red = fmaxf(red, __shfl_xor(red, 16, 64));
      red = fmaxf(red, __shfl_xor(red, 32, 64));

      // defer-max (T13): only rescale when the max grew by more than THR=8
      const float mn = fmaxf(m, red);
      if (!__all(mn - m <= 8.0f)) {
        const float sf = __expf(m - mn);
        m = mn;
        l *= sf;
        #pragma unroll
        for (int nf = 0; nf < 4; ++nf)
          #pragma unroll
          for (int j = 0; j < 4; ++j) oacc[nf][j] *= sf;
      }

      float rs = 0.f;
      #pragma unroll
      for (int nf = 0; nf < 4; ++nf)
        #pragma unroll
        for (int j = 0; j < 4; ++j) {
          const float pj = __expf(sacc[nf][j] - m);
          sacc[nf][j] = pj;
          rs += pj;
        }
      rs += __shfl_xor(rs, 16, 64);
      rs += __shfl_xor(rs, 32, 64);
      l += rs;

      // P -> LDS: packed b64 per nf (4 consecutive kv), la-keyed swizzle
      #pragma unroll
      for (int nf = 0; nf < 4; ++nf) {
        bf16x4 pv;
        #pragma unroll
        for (int j = 0; j < 4; ++j) pv[j] = (bf16_t)sacc[nf][j];
        *(bf16x4*)&sP[wv * 1024 + la * 64 + ((nf * 16 + lb * 4) ^ psw)] = pv;
      }

      // O^T += V^T P^T : mfma(A=Vt rows d, B=P rows q)
      __builtin_amdgcn_s_setprio(1);
      #pragma unroll
      for (int ks = 0; ks < 2; ++ks) {
        const bf16x8 pa = *(const bf16x8*)&sP[wv * 1024 + la * 64 + ((ks * 32 + lb * 8) ^ psw)];
        #pragma unroll
        for (int nf = 0; nf < 4; ++nf) {
          const bf16x8 vb2 = *(const bf16x8*)&sVt[SW((nf * 16 + la) * 64 + ks * 32 + lb * 8)];
          oacc[nf] = __builtin_amdgcn_mfma_f32_16x16x32_bf16(vb2, pa, oacc[nf], 0, 0, 0);
        }
      }
      __builtin_amdgcn_s_setprio(0);

      __syncthreads();   // drains prefetch (vmcnt) + guards buffer overwrite
    }

    // epilogue: O[b,s,h,d] bf16, packed b64 (4 consecutive d per nf)
    const float inv_l = 1.0f / l;
    #pragma unroll
    for (int nf = 0; nf < 4; ++nf) {
      bf16x4 ov;
      #pragma unroll
      for (int j = 0; j < 4; ++j) ov[j] = (bf16_t)(oacc[nf][j] * inv_l);
      const int d0 = nf * 16 + lb * 4;
      *(bf16x4*)&O[(((size_t)b * 2048 + q) * 16 + h) * 64 + d0] = ov;
    }
  }
}

extern "C" void kernel_launch(void* const* d_in, const int* in_sizes, int n_in,
                              void* d_out, int out_size, void* d_ws, size_t ws_size,
                              hipStream_t stream)
{
  const float* x      = (const float*)d_in[0];
  const int*   tokpos = (const int*)d_in[1];
  const float* qw     = (const float*)d_in[2];
  const float* kw     = (const float*)d_in[3];
  const float* vw     = (const float*)d_in[4];
  const float* ow     = (const float*)d_in[5];
  float* out = (float*)d_out;

  const size_t E  = (size_t)4 * 16 * 2048 * 64;  // 8388608 elems per activation
  const size_t W1 = (size_t)1024 * 1024;         // weight elems
  bf16_t* base = (bf16_t*)d_ws;
  bf16_t* Qhi = base;
  bf16_t* Qlo = base + E;
  bf16_t* Khi = base + 2 * E;
  bf16_t* Klo = base + 3 * E;
  bf16_t* Vt  = base + 4 * E;        // [B,H,D,S]
  bf16_t* Xh  = base + 5 * E;
  bf16_t* Xl  = base + 6 * E;
  bf16_t* QWh = base + 7 * E;
  bf16_t* QWl = QWh + W1;
  bf16_t* KWh = QWh + 2 * W1;
  bf16_t* KWl = QWh + 3 * W1;
  bf16_t* VWh = QWh + 4 * W1;
  bf16_t* OWh = QWh + 5 * W1;
  float*  ropeT = (float*)(QWh + 6 * W1);        // 2048*64 floats
  bf16_t* O = Xh;                                 // alias: X dead before attn

  RopeTab tab;
  for (int i = 0; i < 32; ++i)
    tab.inv[i] = (float)pow(10000.0, -(double)i / 32.0);

  // fused pre-passes (splits + rope table)
  prep_k<<<12544, 256, 0, stream>>>(x, qw, kw, vw, ow, tab,
                                    Xh, Xl, QWh, QWl, KWh, KWl, VWh, OWh, ropeT);

  // QKV projections: one dispatch; z=0 merged shared-A Q+K, z=1 V (light)
  gemm_qkv2<<<dim3(64, 8, 2), 512, 0, stream>>>(
      Xh, Xl, QWh, QWl, KWh, KWl, VWh, tokpos, ropeT,
      Qhi, Qlo, Khi, Klo, Vt);
  // attention: 512 persistent blocks x 512 threads
  attn_kernel<<<512, 512, 0, stream>>>(Qhi, Qlo, Khi, Klo, Vt, O);
  // output projection -> fp32 d_out
  gemm_o<<<dim3(64, 8), 256, 0, stream>>>(O, OWh, out);
}

// Round 13
// 241.742 us; speedup vs baseline: 1.1956x; 1.0331x over previous
//
#include <hip/hip_runtime.h>
#include <cmath>

// MHA fused forward, MI355X gfx950.
// R12: REVERT to the R7 configuration -- the measured optimum (241.7us).
// R8-R11 experiments (256-sq counted-vmcnt x2, split launches, shared-A
// merge) all regressed; every component of R7 sits at its measured
// structural ceiling: Q/K proj 103 GF (3-term provably minimal) at the
// m97 884 TF ceiling = 117us; V+O 39us; attn ~70us; prep ~15us (HBM BW).
// Numerics: split-bf16 hi/lo 3-term for Q/K projections and QK^T.

typedef __bf16 bf16_t;
typedef __bf16 bf16x2 __attribute__((ext_vector_type(2)));
typedef __bf16 bf16x4 __attribute__((ext_vector_type(4)));
typedef __bf16 bf16x8 __attribute__((ext_vector_type(8)));
typedef float f32x2 __attribute__((ext_vector_type(2)));
typedef float f32x4 __attribute__((ext_vector_type(4)));
typedef unsigned int u32;
typedef const __attribute__((address_space(1))) u32* gaddr_t;
typedef __attribute__((address_space(3))) u32* saddr_t;

struct RopeTab { float inv[32]; };

// ---------------- fused pre-pass ----------------
__device__ __forceinline__ void split4(const float* __restrict__ in,
                                       bf16_t* __restrict__ hi,
                                       bf16_t* __restrict__ lo, bool LO,
                                       int blk, int tid)
{
  const int i = blk * 256 + tid;
  const f32x4 u = *(const f32x4*)(in + (size_t)i * 4);
  bf16x4 h, l;
  #pragma unroll
  for (int j = 0; j < 4; ++j) {
    const bf16_t hb = (bf16_t)u[j];
    h[j] = hb;
    if (LO) l[j] = (bf16_t)(u[j] - (float)hb);
  }
  *(bf16x4*)(hi + (size_t)i * 4) = h;
  if (LO) *(bf16x4*)(lo + (size_t)i * 4) = l;
}

__global__ __launch_bounds__(256) void prep_k(
    const float* __restrict__ x,  const float* __restrict__ qw,
    const float* __restrict__ kw, const float* __restrict__ vw,
    const float* __restrict__ ow, RopeTab tab,
    bf16_t* __restrict__ Xh,  bf16_t* __restrict__ Xl,
    bf16_t* __restrict__ QWh, bf16_t* __restrict__ QWl,
    bf16_t* __restrict__ KWh, bf16_t* __restrict__ KWl,
    bf16_t* __restrict__ VWh, bf16_t* __restrict__ OWh,
    float* __restrict__ ropeT)
{
  const int bid = blockIdx.x, tid = threadIdx.x;
  if (bid < 8192)       split4(x,  Xh,  Xl,  true,  bid,         tid);
  else if (bid < 9216)  split4(qw, QWh, QWl, true,  bid - 8192,  tid);
  else if (bid < 10240) split4(kw, KWh, KWl, true,  bid - 9216,  tid);
  else if (bid < 11264) split4(vw, VWh, nullptr, false, bid - 10240, tid);
  else if (bid < 12288) split4(ow, OWh, nullptr, false, bid - 11264, tid);
  else {
    const int i = (bid - 12288) * 256 + tid;   // 2048*32 entries
    const int p = i >> 5, d2 = i & 31;
    float sn, cs;
    sincosf((float)p * tab.inv[d2], &sn, &cs);
    ropeT[(size_t)i * 2]     = cs;
    ropeT[(size_t)i * 2 + 1] = sn;
  }
}

// ------------- QKV projection GEMM (B^T), m97 single-buffer -------------
// z=0: Q (3-seg split, RoPE epilogue), z=1: K (same), z=2: V (1 seg, V^T out).
__global__ __launch_bounds__(256, 4) void gemm_qkv(
    const bf16_t* __restrict__ Xh, const bf16_t* __restrict__ Xl,
    const bf16_t* __restrict__ QWh, const bf16_t* __restrict__ QWl,
    const bf16_t* __restrict__ KWh, const bf16_t* __restrict__ KWl,
    const bf16_t* __restrict__ VWh,
    const int* __restrict__ tokpos, const float* __restrict__ ropeT,
    bf16_t* __restrict__ Oq_h, bf16_t* __restrict__ Oq_l,
    bf16_t* __restrict__ Ok_h, bf16_t* __restrict__ Ok_l,
    bf16_t* __restrict__ Vt)
{
  __shared__ __align__(16) bf16_t sA[128 * 64];
  __shared__ __align__(16) bf16_t sB[128 * 64];

  const int tid = threadIdx.x;
  const int lane = tid & 63, wv = tid >> 6;
  const int wr = wv >> 1, wc = wv & 1;
  const int la = lane & 15, lb = lane >> 4;
  const int row0 = blockIdx.x * 128, col0 = blockIdx.y * 128;
  const int z = blockIdx.z;

  const int srow = wv * 32 + (lane >> 3);   // + i*8
  const int schk = lane & 7;                // physical 16B chunk within row

  f32x4 acc[4][4] = {};

  const int NT = (z == 2) ? 16 : 48;        // steps of BK=64 (3 segs for Q/K)

  for (int t = 0; t < NT; ++t) {
    const int seg = t >> 4;
    const int k0 = (t & 15) << 6;
    const bf16_t* Ap = (z < 2 && seg == 2) ? Xl : Xh;
    const bf16_t* Wp = (z == 2) ? VWh
                     : (z == 1) ? ((seg == 1) ? KWl : KWh)
                                : ((seg == 1) ? QWl : QWh);
    __syncthreads();
    #pragma unroll
    for (int i = 0; i < 4; ++i) {
      const int r = srow + i * 8;
      const int cs_ = (schk ^ (r & 7)) * 8;       // inverse-swizzled source col
      __builtin_amdgcn_global_load_lds(
          (gaddr_t)(Ap + (size_t)(row0 + r) * 1024 + k0 + cs_),
          (saddr_t)(sA + wv * 2048 + i * 512), 16, 0, 0);
      __builtin_amdgcn_global_load_lds(
          (gaddr_t)(Wp + (size_t)(col0 + r) * 1024 + k0 + cs_),
          (saddr_t)(sB + wv * 2048 + i * 512), 16, 0, 0);
    }
    __syncthreads();

    #pragma unroll
    for (int ks = 0; ks < 2; ++ks) {
      bf16x8 af[4];
      #pragma unroll
      for (int m = 0; m < 4; ++m) {
        const int r = wr * 64 + m * 16 + la;
        af[m] = *(const bf16x8*)&sA[r * 64 + (((ks * 4 + lb) ^ (la & 7)) * 8)];
      }
      #pragma unroll
      for (int n = 0; n < 4; ++n) {
        const int r = wc * 64 + n * 16 + la;
        const bf16x8 bfr = *(const bf16x8*)&sB[r * 64 + (((ks * 4 + lb) ^ (la & 7)) * 8)];
        #pragma unroll
        for (int m = 0; m < 4; ++m)
          acc[m][n] = __builtin_amdgcn_mfma_f32_16x16x32_bf16(af[m], bfr, acc[m][n], 0, 0, 0);
      }
    }
  }

  // ---- epilogue ----
  #pragma unroll
  for (int n = 0; n < 4; ++n) {
    const int gn = col0 + wc * 64 + n * 16 + la;
    #pragma unroll
    for (int m = 0; m < 4; ++m) {
      const int gm0 = row0 + wr * 64 + m * 16 + lb * 4;
      if (z == 2) {
        // V^T layout: [B,H,D,S], packed 8B stores
        const int b = gm0 >> 11, s0 = gm0 & 2047;
        const int h = gn >> 6, d = gn & 63;
        bf16x4 v;
        #pragma unroll
        for (int j = 0; j < 4; ++j) v[j] = (bf16_t)acc[m][n][j];
        *(bf16x4*)&Vt[(((size_t)b * 16 + h) * 64 + d) * 2048 + s0] = v;
      } else {
        const int d = gn & 63, h = gn >> 6;
        const bool odd = d & 1;
        bf16_t* Oh = z ? Ok_h : Oq_h;
        bf16_t* Ol = z ? Ok_l : Oq_l;
        #pragma unroll
        for (int j = 0; j < 4; ++j) {
          const int gm = gm0 + j;
          const float t = acc[m][n][j];
          const float other = __shfl_xor(t, 1, 64);   // partner column d^1
          const int pos = tokpos[gm];
          const f32x2 cs2 = *(const f32x2*)&ropeT[((size_t)pos << 6) + ((d >> 1) << 1)];
          const float r = odd ? (other * cs2[1] + t * cs2[0])
                              : (t * cs2[0] - other * cs2[1]);
          const bf16_t hb = (bf16_t)r;
          const int b = gm >> 11, s = gm & 2047;
          const size_t oi = (((size_t)b * 16 + h) * 2048 + s) * 64 + d;
          Oh[oi] = hb;
          Ol[oi] = (bf16_t)(r - (float)hb);
        }
      }
    }
  }
}

// ------------- O projection GEMM (bf16 A, fp32 out), m97 single-buffer -------------
__global__ __launch_bounds__(256, 4) void gemm_o(
    const bf16_t* __restrict__ Ag, const bf16_t* __restrict__ Wg,
    float* __restrict__ Of)
{
  __shared__ __align__(16) bf16_t sA[128 * 64];
  __shared__ __align__(16) bf16_t sB[128 * 64];

  const int tid = threadIdx.x;
  const int lane = tid & 63, wv = tid >> 6;
  const int wr = wv >> 1, wc = wv & 1;
  const int la = lane & 15, lb = lane >> 4;
  const int row0 = blockIdx.x * 128, col0 = blockIdx.y * 128;

  const int srow = wv * 32 + (lane >> 3);
  const int schk = lane & 7;

  f32x4 acc[4][4] = {};

  for (int t = 0; t < 16; ++t) {
    const int k0 = t << 6;
    __syncthreads();
    #pragma unroll
    for (int i = 0; i < 4; ++i) {
      const int r = srow + i * 8;
      const int cs_ = (schk ^ (r & 7)) * 8;
      __builtin_amdgcn_global_load_lds(
          (gaddr_t)(Ag + (size_t)(row0 + r) * 1024 + k0 + cs_),
          (saddr_t)(sA + wv * 2048 + i * 512), 16, 0, 0);
      __builtin_amdgcn_global_load_lds(
          (gaddr_t)(Wg + (size_t)(col0 + r) * 1024 + k0 + cs_),
          (saddr_t)(sB + wv * 2048 + i * 512), 16, 0, 0);
    }
    __syncthreads();
    #pragma unroll
    for (int ks = 0; ks < 2; ++ks) {
      bf16x8 af[4];
      #pragma unroll
      for (int m = 0; m < 4; ++m) {
        const int r = wr * 64 + m * 16 + la;
        af[m] = *(const bf16x8*)&sA[r * 64 + (((ks * 4 + lb) ^ (la & 7)) * 8)];
      }
      #pragma unroll
      for (int n = 0; n < 4; ++n) {
        const int r = wc * 64 + n * 16 + la;
        const bf16x8 bfr = *(const bf16x8*)&sB[r * 64 + (((ks * 4 + lb) ^ (la & 7)) * 8)];
        #pragma unroll
        for (int m = 0; m < 4; ++m)
          acc[m][n] = __builtin_amdgcn_mfma_f32_16x16x32_bf16(af[m], bfr, acc[m][n], 0, 0, 0);
      }
    }
  }

  #pragma unroll
  for (int n = 0; n < 4; ++n) {
    const int gn = col0 + wc * 64 + n * 16 + la;
    #pragma unroll
    for (int m = 0; m < 4; ++m) {
      const int gm0 = row0 + wr * 64 + m * 16 + lb * 4;
      #pragma unroll
      for (int j = 0; j < 4; ++j)
        Of[(size_t)(gm0 + j) * 1024 + gn] = acc[m][n][j];
    }
  }
}

// XOR swizzle for 64-elem-wide bf16 LDS tiles (row = 128B).
__device__ __forceinline__ int SW(int e) { return e ^ (((e >> 6) & 7) << 3); }

// Flash attention, causal, split-bf16 QK^T, swapped operands (R4 structure).
// 512 persistent blocks x 512 threads; paired-qb (uniform 34 tiles/block).
__global__ __launch_bounds__(512, 4) void attn_kernel(
    const bf16_t* __restrict__ Qhi, const bf16_t* __restrict__ Qlo,
    const bf16_t* __restrict__ Khi, const bf16_t* __restrict__ Klo,
    const bf16_t* __restrict__ Vt, bf16_t* __restrict__ O)
{
  // [buf][ Kh(4096) | Kl(4096) | Vt(4096) ]
  __shared__ __align__(16) bf16_t sKV[2][3 * 4096];
  __shared__ __align__(16) bf16_t sP[8 * 1024];   // per-wave [q=la][kv], la-swizzled

  // XCD-aware remap: 512 blocks = 64 bh x 8 qb-pairs
  const int linear = (int)blockIdx.x;
  const int xcd = linear & 7;
  const int pos = linear >> 3;            // 0..63
  const int bh  = xcd * 8 + (pos >> 3);   // [0,64)
  const int p   = pos & 7;                // qb pair index
  const int b = bh >> 4, h = bh & 15;

  const size_t base = (size_t)bh * 2048 * 64;
  const bf16_t* Qh_ = Qhi + base;
  const bf16_t* Ql_ = Qlo + base;
  const bf16_t* Kh_ = Khi + base;
  const bf16_t* Kl_ = Klo + base;
  const bf16_t* Vt_ = Vt + base;    // [64 d][2048 s]

  const int tid = threadIdx.x, wv = tid >> 6, lane = tid & 63;
  const int la = lane & 15, lb = lane >> 4;

  // staging geometry (per thread, 3 x 16B): covers 24KB over 512 threads
  const int sr   = wv * 8 + (lane >> 3);        // tile row 0..63
  const int scsw = (lane & 7) ^ (sr & 7);       // inverse-swizzled 16B chunk
  const int ssrc = sr * 64 + scsw * 8;          // K source elem offset in tile
  const int se0  = wv * 512;                    // wave-uniform LDS chunk base
  const int psw  = (la & 7) << 3;               // sP swizzle key (kv bits 3..5)

  auto STAGE = [&](int kvb, int buf) {
    const int kv0 = kvb * 64;
    bf16_t* dst = &sKV[buf][0];
    __builtin_amdgcn_global_load_lds((gaddr_t)(Kh_ + (size_t)kv0 * 64 + ssrc),
                                     (saddr_t)(dst + se0), 16, 0, 0);
    __builtin_amdgcn_global_load_lds((gaddr_t)(Kl_ + (size_t)kv0 * 64 + ssrc),
                                     (saddr_t)(dst + 4096 + se0), 16, 0, 0);
    __builtin_amdgcn_global_load_lds((gaddr_t)(Vt_ + (size_t)sr * 2048 + kv0 + scsw * 8),
                                     (saddr_t)(dst + 8192 + se0), 16, 0, 0);
  };

  for (int half = 0; half < 2; ++half) {
    const int qb = half ? p : 15 - p;
    const int q = qb * 128 + wv * 16 + la;   // this lane's q row (global)
    bf16x8 qh[2], ql[2];
    #pragma unroll
    for (int kf = 0; kf < 2; ++kf) {
      qh[kf] = *(const bf16x8*)&Qh_[(size_t)q * 64 + kf * 32 + lb * 8];
      ql[kf] = *(const bf16x8*)&Ql_[(size_t)q * 64 + kf * 32 + lb * 8];
    }

    f32x4 oacc[4] = {};       // oacc[nf][j] = O^T[d = nf*16+lb*4+j][q = la]
    float m = -1e30f, l = 0.f;
    const int nt = 2 * qb + 2;

    STAGE(0, 0);
    __syncthreads();

    for (int kvb = 0; kvb < nt; ++kvb) {
      const int kv0 = kvb * 64;
      if (kvb + 1 < nt) STAGE(kvb + 1, (kvb + 1) & 1);

      const bf16_t* sKh = &sKV[kvb & 1][0];
      const bf16_t* sKl = sKh + 4096;
      const bf16_t* sVt = sKh + 8192;

      // S^T = K Q^T (3-term split): sacc[nf][j] at kv = kv0+nf*16+lb*4+j
      f32x4 sacc[4] = {};
      __builtin_amdgcn_s_setprio(1);
      #pragma unroll
      for (int nf = 0; nf < 4; ++nf) {
        #pragma unroll
        for (int kf = 0; kf < 2; ++kf) {
          const int rr = SW((nf * 16 + la) * 64 + kf * 32 + lb * 8);
          const bf16x8 kh = *(const bf16x8*)&sKh[rr];
          const bf16x8 kl = *(const bf16x8*)&sKl[rr];
          sacc[nf] = __builtin_amdgcn_mfma_f32_16x16x32_bf16(kh, qh[kf], sacc[nf], 0, 0, 0);
          sacc[nf] = __builtin_amdgcn_mfma_f32_16x16x32_bf16(kl, qh[kf], sacc[nf], 0, 0, 0);
          sacc[nf] = __builtin_amdgcn_mfma_f32_16x16x32_bf16(kh, ql[kf], sacc[nf], 0, 0, 0);
        }
      }
      __builtin_amdgcn_s_setprio(0);

      // mask + scale (mask only possibly-diagonal tiles: kvb >= 2*qb)
      if (kvb >= 2 * qb) {
        #pragma unroll
        for (int nf = 0; nf < 4; ++nf)
          #pragma unroll
          for (int j = 0; j < 4; ++j) {
            const int kvi = kv0 + nf * 16 + lb * 4 + j;
            sacc[nf][j] = (kvi <= q) ? sacc[nf][j] * 0.125f : -1e30f;
          }
      } else {
        #pragma unroll
        for (int nf = 0; nf < 4; ++nf)
          #pragma unroll
          for (int j = 0; j < 4; ++j) sacc[nf][j] *= 0.125f;
      }

      // row softmax: in-lane 16, then combine lb groups (lanes ^16, ^32)
      float red = sacc[0][0];
      #pragma unroll
      for (int nf = 0; nf < 4; ++nf)
        #pragma unroll
        for (int j = 0; j < 4; ++j) red = fmaxf(red, sacc[nf][j]);
      red = fmaxf(red, __shfl_xor(red, 16, 64));
      red = fmaxf(red, __shfl_xor(red, 32, 64));

      // defer-max (T13): only rescale when the max grew by more than THR=8
      const float mn = fmaxf(m, red);
      if (!__all(mn - m <= 8.0f)) {
        const float sf = __expf(m - mn);
        m = mn;
        l *= sf;
        #pragma unroll
        for (int nf = 0; nf < 4; ++nf)
          #pragma unroll
          for (int j = 0; j < 4; ++j) oacc[nf][j] *= sf;
      }

      float rs = 0.f;
      #pragma unroll
      for (int nf = 0; nf < 4; ++nf)
        #pragma unroll
        for (int j = 0; j < 4; ++j) {
          const float pj = __expf(sacc[nf][j] - m);
          sacc[nf][j] = pj;
          rs += pj;
        }
      rs += __shfl_xor(rs, 16, 64);
      rs += __shfl_xor(rs, 32, 64);
      l += rs;

      // P -> LDS: packed b64 per nf (4 consecutive kv), la-keyed swizzle
      #pragma unroll
      for (int nf = 0; nf < 4; ++nf) {
        bf16x4 pv;
        #pragma unroll
        for (int j = 0; j < 4; ++j) pv[j] = (bf16_t)sacc[nf][j];
        *(bf16x4*)&sP[wv * 1024 + la * 64 + ((nf * 16 + lb * 4) ^ psw)] = pv;
      }

      // O^T += V^T P^T : mfma(A=Vt rows d, B=P rows q)
      __builtin_amdgcn_s_setprio(1);
      #pragma unroll
      for (int ks = 0; ks < 2; ++ks) {
        const bf16x8 pa = *(const bf16x8*)&sP[wv * 1024 + la * 64 + ((ks * 32 + lb * 8) ^ psw)];
        #pragma unroll
        for (int nf = 0; nf < 4; ++nf) {
          const bf16x8 vb2 = *(const bf16x8*)&sVt[SW((nf * 16 + la) * 64 + ks * 32 + lb * 8)];
          oacc[nf] = __builtin_amdgcn_mfma_f32_16x16x32_bf16(vb2, pa, oacc[nf], 0, 0, 0);
        }
      }
      __builtin_amdgcn_s_setprio(0);

      __syncthreads();   // drains prefetch (vmcnt) + guards buffer overwrite
    }

    // epilogue: O[b,s,h,d] bf16, packed b64 (4 consecutive d per nf)
    const float inv_l = 1.0f / l;
    #pragma unroll
    for (int nf = 0; nf < 4; ++nf) {
      bf16x4 ov;
      #pragma unroll
      for (int j = 0; j < 4; ++j) ov[j] = (bf16_t)(oacc[nf][j] * inv_l);
      const int d0 = nf * 16 + lb * 4;
      *(bf16x4*)&O[(((size_t)b * 2048 + q) * 16 + h) * 64 + d0] = ov;
    }
  }
}

extern "C" void kernel_launch(void* const* d_in, const int* in_sizes, int n_in,
                              void* d_out, int out_size, void* d_ws, size_t ws_size,
                              hipStream_t stream)
{
  const float* x      = (const float*)d_in[0];
  const int*   tokpos = (const int*)d_in[1];
  const float* qw     = (const float*)d_in[2];
  const float* kw     = (const float*)d_in[3];
  const float* vw     = (const float*)d_in[4];
  const float* ow     = (const float*)d_in[5];
  float* out = (float*)d_out;

  const size_t E  = (size_t)4 * 16 * 2048 * 64;  // 8388608 elems per activation
  const size_t W1 = (size_t)1024 * 1024;         // weight elems
  bf16_t* base = (bf16_t*)d_ws;
  bf16_t* Qhi = base;
  bf16_t* Qlo = base + E;
  bf16_t* Khi = base + 2 * E;
  bf16_t* Klo = base + 3 * E;
  bf16_t* Vt  = base + 4 * E;        // [B,H,D,S]
  bf16_t* Xh  = base + 5 * E;
  bf16_t* Xl  = base + 6 * E;
  bf16_t* QWh = base + 7 * E;
  bf16_t* QWl = QWh + W1;
  bf16_t* KWh = QWh + 2 * W1;
  bf16_t* KWl = QWh + 3 * W1;
  bf16_t* VWh = QWh + 4 * W1;
  bf16_t* OWh = QWh + 5 * W1;
  float*  ropeT = (float*)(QWh + 6 * W1);        // 2048*64 floats
  bf16_t* O = Xh;                                 // alias: X dead before attn

  RopeTab tab;
  for (int i = 0; i < 32; ++i)
    tab.inv[i] = (float)pow(10000.0, -(double)i / 32.0);

  // fused pre-passes (splits + rope table)
  prep_k<<<12544, 256, 0, stream>>>(x, qw, kw, vw, ow, tab,
                                    Xh, Xl, QWh, QWl, KWh, KWl, VWh, OWh, ropeT);

  // Q, K, V projections in one launch (z selects); RoPE fused for Q/K
  gemm_qkv<<<dim3(64, 8, 3), 256, 0, stream>>>(
      Xh, Xl, QWh, QWl, KWh, KWl, VWh, tokpos, ropeT,
      Qhi, Qlo, Khi, Klo, Vt);
  // attention: 512 persistent blocks x 512 threads (2 blocks/CU exactly)
  attn_kernel<<<512, 512, 0, stream>>>(Qhi, Qlo, Khi, Klo, Vt, O);
  // output projection -> fp32 d_out
  gemm_o<<<dim3(64, 8), 256, 0, stream>>>(O, OWh, out);
}